// Round 7
// baseline (325.455 us; speedup 1.0000x reference)
//
#include <hip/hip_runtime.h>

typedef unsigned short u16;
typedef __attribute__((ext_vector_type(8))) __bf16 bf16x8;
typedef __attribute__((ext_vector_type(8))) short short8;
typedef __attribute__((ext_vector_type(4))) float f32x4;
typedef __attribute__((ext_vector_type(4))) unsigned short ushort4v;

__device__ __forceinline__ u16 f2bf(float f) {
  unsigned u = __builtin_bit_cast(unsigned, f);
  u += 0x7fffu + ((u >> 16) & 1u);
  return (u16)(u >> 16);
}

__device__ __forceinline__ float exp2_hw(float x) {
  float r; asm("v_exp_f32 %0, %1" : "=v"(r) : "v"(x)); return r;
}
__device__ __forceinline__ unsigned cvt_pk_bf16(float a, float b) {
  unsigned r; asm("v_cvt_pk_bf16_f32 %0, %1, %2" : "=v"(r) : "v"(a), "v"(b)); return r;
}

__device__ __forceinline__ void gload_lds16(const void* g, void* l) {
  __builtin_amdgcn_global_load_lds(
      (__attribute__((address_space(1))) void*)g,
      (__attribute__((address_space(3))) void*)l, 16, 0, 0);
}

__device__ __forceinline__ void BAR() {
  asm volatile("" ::: "memory");
  __builtin_amdgcn_s_barrier();
  asm volatile("" ::: "memory");
}

#define MFMA16(a, b, c) __builtin_amdgcn_mfma_f32_16x16x32_bf16(a, b, c, 0, 0, 0)

// scale folded into Q at GEMM1 epilogue: 1/sqrt(64) * log2(e)
#define QSCALE 0.1803368801111204f

// ---------------- merged prep kernel ----------------

__global__ __launch_bounds__(256)
void prep_kernel(const float* __restrict__ x, const float* __restrict__ Wq,
                 const float* __restrict__ Wk, const float* __restrict__ Wv,
                 const float* __restrict__ pw, u16* __restrict__ Xb,
                 u16* __restrict__ Wcat, u16* __restrict__ PWt) {
  const int b = blockIdx.x, tid = threadIdx.x;
  if (b < 8192) {
    int i = b * 256 + tid;
    float4 v = ((const float4*)x)[i];
    union { u16 u[4]; uint2 v2; } r;
    r.u[0] = f2bf(v.x); r.u[1] = f2bf(v.y); r.u[2] = f2bf(v.z); r.u[3] = f2bf(v.w);
    ((uint2*)Xb)[i] = r.v2;
  } else if (b < 8960) {
    __shared__ u16 lds[64 * 68];
    int bb = b - 8192;
    int sel = bb >> 8, rem = bb & 255;
    int h = rem >> 4, e0 = (rem & 15) * 64;
    const float* W = (sel == 0) ? Wq : (sel == 1) ? Wk : Wv;
    const float* src = W + ((size_t)h * 1024 + e0) * 64;
#pragma unroll
    for (int i = 0; i < 4; i++) {
      int idx = i * 1024 + tid * 4;
      int e = idx >> 6, hs = idx & 63;
      float4 v = *(const float4*)&src[idx];
      u16* d = &lds[e * 68 + hs];
      d[0] = f2bf(v.x); d[1] = f2bf(v.y); d[2] = f2bf(v.z); d[3] = f2bf(v.w);
    }
    __syncthreads();
#pragma unroll
    for (int i = 0; i < 2; i++) {
      int u = i * 256 + tid;
      int hs = u >> 3, ec = u & 7;
      union { u16 q[8]; uint4 v; } ou;
#pragma unroll
      for (int e = 0; e < 8; e++) ou.q[e] = lds[(ec * 8 + e) * 68 + hs];
      size_t n = (size_t)sel * 1024 + h * 64 + hs;
      *(uint4*)&Wcat[n * 1024 + e0 + ec * 8] = ou.v;
    }
  } else {
    int i = (b - 8960) * 256 + tid;
    float4 v = ((const float4*)pw)[i];
    union { u16 u[4]; uint2 v2; } r;
    r.u[0] = f2bf(v.x); r.u[1] = f2bf(v.y); r.u[2] = f2bf(v.z); r.u[3] = f2bf(v.w);
    ((uint2*)PWt)[i] = r.v2;
  }
}

// ---------------- triple-buffered 128x256 GEMM: C = A[M,K] * BT[N,K]^T ----

template<int OUT_BF16>
__global__ __launch_bounds__(512, 2)
void gemm3b(const u16* __restrict__ A, const u16* __restrict__ BT,
            void* __restrict__ Cout, const float* __restrict__ bias,
            int M, int N, int K, int gy, int qcols) {
  __shared__ u16 a_lds[3][128 * 64];
  __shared__ u16 b_lds[3][256 * 64];
  const int nwg = gridDim.x;
  const int qch = nwg >> 3;
  const int wg = (blockIdx.x & 7) * qch + (blockIdx.x >> 3);
  const int bx = wg / gy, by = wg % gy;
  const int tid = threadIdx.x;
  const int lane = tid & 63;
  const int w = tid >> 6;
  const int wr = w >> 2, wc = w & 3;
  const int mBase = by * 128, nBase = bx * 256;
  const int l15 = lane & 15, l4 = lane >> 4;
  const int nkt = K >> 6;

  f32x4 acc[4][4] = {};

  auto STAGE_A = [&](int s, int kt) {
#pragma unroll
    for (int j = 0; j < 2; j++) {
      int e = j * 4096 + tid * 8;
      int row = e >> 6;
      int c = ((e >> 3) & 7) ^ (row & 7);
      gload_lds16(A + (size_t)(mBase + row) * K + kt * 64 + c * 8, &a_lds[s][e]);
    }
  };
  auto STAGE_B = [&](int s, int kt) {
#pragma unroll
    for (int j = 0; j < 4; j++) {
      int e = j * 4096 + tid * 8;
      int row = e >> 6;
      int c = ((e >> 3) & 7) ^ (row & 7);
      gload_lds16(BT + (size_t)(nBase + row) * K + kt * 64 + c * 8, &b_lds[s][e]);
    }
  };

  STAGE_A(0, 0); STAGE_B(0, 0);
  STAGE_A(1, 1); STAGE_B(1, 1);
  asm volatile("s_waitcnt vmcnt(6)" ::: "memory");
  BAR();

  int s0 = 0, s1 = 1, s2 = 2;
  for (int t = 0; t < nkt; t++) {
    const int t2 = (t + 2 < nkt) ? t + 2 : t + 2 - nkt;
    bf16x8 AF[4][2], BF[2][2];

#pragma unroll
    for (int m = 0; m < 4; m++) {
      int row = wr * 64 + m * 16 + l15;
#pragma unroll
      for (int ks = 0; ks < 2; ks++) {
        int ch = (ks * 4 + l4) ^ (row & 7);
        AF[m][ks] = *(const bf16x8*)&a_lds[s0][row * 64 + ch * 8];
      }
    }
#pragma unroll
    for (int n = 0; n < 2; n++) {
      int row = wc * 64 + n * 16 + l15;
#pragma unroll
      for (int ks = 0; ks < 2; ks++) {
        int ch = (ks * 4 + l4) ^ (row & 7);
        BF[n][ks] = *(const bf16x8*)&b_lds[s0][row * 64 + ch * 8];
      }
    }
    STAGE_A(s2, t2);
    STAGE_B(s2, t2);
    __builtin_amdgcn_s_setprio(1);
#pragma unroll
    for (int m = 0; m < 4; m++)
#pragma unroll
      for (int n = 0; n < 2; n++) {
        acc[m][n] = MFMA16(AF[m][0], BF[n][0], acc[m][n]);
        acc[m][n] = MFMA16(AF[m][1], BF[n][1], acc[m][n]);
      }
    __builtin_amdgcn_s_setprio(0);

#pragma unroll
    for (int n = 0; n < 2; n++) {
      int row = wc * 64 + 32 + n * 16 + l15;
#pragma unroll
      for (int ks = 0; ks < 2; ks++) {
        int ch = (ks * 4 + l4) ^ (row & 7);
        BF[n][ks] = *(const bf16x8*)&b_lds[s0][row * 64 + ch * 8];
      }
    }
    __builtin_amdgcn_s_setprio(1);
#pragma unroll
    for (int m = 0; m < 4; m++)
#pragma unroll
      for (int n = 0; n < 2; n++) {
        acc[m][2 + n] = MFMA16(AF[m][0], BF[n][0], acc[m][2 + n]);
        acc[m][2 + n] = MFMA16(AF[m][1], BF[n][1], acc[m][2 + n]);
      }
    __builtin_amdgcn_s_setprio(0);

    asm volatile("s_waitcnt vmcnt(6)" ::: "memory");
    BAR();
    int tmp = s0; s0 = s1; s1 = s2; s2 = tmp;
  }

#pragma unroll
  for (int mi = 0; mi < 4; mi++) {
    int row = mBase + wr * 64 + mi * 16 + l4 * 4;
#pragma unroll
    for (int ni = 0; ni < 4; ni++) {
      int col = nBase + wc * 64 + ni * 16 + l15;
      float scl = (col < qcols) ? QSCALE : 1.f;
#pragma unroll
      for (int j = 0; j < 4; j++) {
        float v = acc[mi][ni][j];
        if (OUT_BF16) {
          ((u16*)Cout)[(size_t)(row + j) * N + col] = f2bf(v * scl);
        } else {
          ((float*)Cout)[(size_t)(row + j) * N + col] = v + bias[col];
        }
      }
    }
  }
}

// ---------------- V transpose: VT[hb][d][t] from QKV V-section ----------------

__global__ __launch_bounds__(256)
void vt_build(const u16* __restrict__ qkv, u16* __restrict__ vt) {
  __shared__ u16 lds[64 * 66];
  const int hb = blockIdx.x >> 5, tc = blockIdx.x & 31;
  const int t0 = tc * 64, tid = threadIdx.x;
#pragma unroll
  for (int i = 0; i < 2; i++) {
    int idx = i * 2048 + tid * 8;
    int tl = idx >> 6, d0 = idx & 63;
    int r = hb * 2048 + t0 + tl;
    const u16* src = &qkv[(size_t)(r >> 4) * 3072 + 2048 + (r & 15) * 64 + d0];
    uint4 v = *(const uint4*)src;
    u16* dst = &lds[tl * 66 + d0];
    *(unsigned*)(dst + 0) = v.x; *(unsigned*)(dst + 2) = v.y;
    *(unsigned*)(dst + 4) = v.z; *(unsigned*)(dst + 6) = v.w;
  }
  __syncthreads();
#pragma unroll
  for (int i = 0; i < 2; i++) {
    int idx = i * 2048 + tid * 8;
    int d = idx >> 6, tl0 = idx & 63;
    union { u16 u[8]; uint4 v; } ou;
#pragma unroll
    for (int e = 0; e < 8; e++) ou.u[e] = lds[(tl0 + e) * 66 + d];
    *(uint4*)&vt[(size_t)hb * 131072 + (size_t)d * 2048 + t0 + tl0] = ou.v;
  }
}

// ---------------- flash attention (causal), swapped-operand, no-max softmax --
// P lives in the just-consumed K LDS buffer (dead after QK reads + barrier A):
// per-wave 2 KB slice, two 32x32 k-halves processed sequentially.
// LDS = 32 KiB -> 4 blocks/CU (VGPR-capped via launch_bounds(256,4)).

__global__ __launch_bounds__(256, 4)
void attn_kernel(const u16* __restrict__ qkv, const u16* __restrict__ vtg,
                 u16* __restrict__ att) {
  __shared__ u16 k_lds[2][64 * 64];
  __shared__ u16 v_lds[2][64 * 64];

  const int wg = (blockIdx.x & 7) * 128 + (blockIdx.x >> 3);  // XCD-bijective swizzle
  const int hb = wg >> 4;
  const int qb = 15 - (wg & 15);                              // heavy blocks first
  const int tid = threadIdx.x;
  const int lane = tid & 63, w = tid >> 6;
  const int l15 = lane & 15, l4 = lane >> 4;
  const int qbase = qb * 128 + w * 32;
  const int nkt = 2 * qb + 2;
  const int wbase = w * 1024;          // per-wave 2KB (1024 u16) P slice

  bf16x8 aQ[2][2];
#pragma unroll
  for (int qs = 0; qs < 2; qs++) {
    int t = qbase + qs * 16 + l15;
    int r = hb * 2048 + t;
    size_t base = (size_t)(r >> 4) * 3072 + (r & 15) * 64;
#pragma unroll
    for (int kc = 0; kc < 2; kc++)
      aQ[qs][kc] = *(const bf16x8*)&qkv[base + kc * 32 + l4 * 8];
  }

  f32x4 o[2][4] = {};
  float lp[2] = {0.f, 0.f};   // per-lane partial sums; reduced once in epilogue

  auto STAGE = [&](int buf, int kt) {
#pragma unroll
    for (int i = 0; i < 2; i++) {
      int U = i * 2048 + tid * 8;
      int row = U >> 6;
      int chunk = ((U >> 3) & 7) ^ (row & 7);
      int rK = hb * 2048 + kt * 64 + row;
      gload_lds16(&qkv[(size_t)(rK >> 4) * 3072 + 1024 + (rK & 15) * 64 + chunk * 8],
                  &k_lds[buf][U]);
    }
#pragma unroll
    for (int i = 0; i < 2; i++) {
      int U = i * 2048 + tid * 8;
      int row = U >> 6;
      int chunk = ((U >> 3) & 7) ^ (row & 7);
      gload_lds16(&vtg[(size_t)hb * 131072 + (size_t)row * 2048 + kt * 64 + chunk * 8],
                  &v_lds[buf][U]);
    }
  };

  STAGE(0, 0);
  asm volatile("s_waitcnt vmcnt(0)" ::: "memory");
  BAR();

  for (int kt = 0; kt < nkt; kt++) {
    if (kt + 1 < nkt) STAGE((kt + 1) & 1, kt + 1);
    const int cur = kt & 1;
    const bool active = (kt * 64 <= qbase + 31);

    // QK fragment reads: must ALL complete before any wave writes P into
    // k_lds[cur] -> lgkmcnt(0) + barrier A.
    bf16x8 kf[4][2];
    if (active) {
#pragma unroll
      for (int n = 0; n < 4; n++) {
        int row = n * 16 + l15;
        int sw = (row & 7) << 3;
        kf[n][0] = *(const bf16x8*)&k_lds[cur][row * 64 + ((0 + l4 * 8) ^ sw)];
        kf[n][1] = *(const bf16x8*)&k_lds[cur][row * 64 + ((32 + l4 * 8) ^ sw)];
      }
    }
    asm volatile("s_waitcnt lgkmcnt(0)" ::: "memory");
    BAR();   // barrier A: k_lds[cur] fully consumed; safe to reuse for P

    if (active) {
      f32x4 st[4][2];
      __builtin_amdgcn_s_setprio(1);
#pragma unroll
      for (int n = 0; n < 4; n++)
#pragma unroll
        for (int qs = 0; qs < 2; qs++) {
          f32x4 a = {0.f, 0.f, 0.f, 0.f};
          a = MFMA16(kf[n][0], aQ[qs][0], a);
          a = MFMA16(kf[n][1], aQ[qs][1], a);
          st[n][qs] = a;
        }
      __builtin_amdgcn_s_setprio(0);

      const bool full = (kt * 64 + 63 <= qbase);
      // two k-halves: softmax half -> P write (2KB slice) -> PV half
#pragma unroll
      for (int h = 0; h < 2; h++) {
#pragma unroll
        for (int qs = 0; qs < 2; qs++) {
          int q = qbase + qs * 16 + l15;
          int r = qs * 16 + l15;
#pragma unroll
          for (int nn = 0; nn < 2; nn++) {
            int n = h * 2 + nn;
            float p[4];
#pragma unroll
            for (int j = 0; j < 4; j++) {
              float v = st[n][qs][j];
              if (!full) {
                int k = kt * 64 + n * 16 + l4 * 4 + j;
                v = (k > q) ? -INFINITY : v;
              }
              p[j] = exp2_hw(v);
              lp[qs] += p[j];
            }
            uint2 pk;
            pk.x = cvt_pk_bf16(p[0], p[1]);
            pk.y = cvt_pk_bf16(p[2], p[3]);
            int cw = ((nn * 2 + (l4 >> 1)) ^ (r & 3));
            *(uint2*)&k_lds[cur][wbase + r * 32 + cw * 8 + (l4 & 1) * 4] = pk;
          }
        }
        // PV for this k-half
        bf16x8 pf[2];
#pragma unroll
        for (int qs = 0; qs < 2; qs++) {
          int r = qs * 16 + l15;
          int cr = l4 ^ (r & 3);
          pf[qs] = *(const bf16x8*)&k_lds[cur][wbase + r * 32 + cr * 8];
        }
        __builtin_amdgcn_s_setprio(1);
#pragma unroll
        for (int nd = 0; nd < 4; nd++) {
          int row = nd * 16 + l15;
          int sw = (row & 7) << 3;
          bf16x8 vf = *(const bf16x8*)&v_lds[cur][row * 64 + ((h * 32 + l4 * 8) ^ sw)];
#pragma unroll
          for (int qs = 0; qs < 2; qs++)
            o[qs][nd] = MFMA16(vf, pf[qs], o[qs][nd]);
        }
        __builtin_amdgcn_s_setprio(0);
      }
    }
    asm volatile("s_waitcnt vmcnt(0)" ::: "memory");
    BAR();   // barrier B: staging landed, all LDS reads of cur done
  }

  // epilogue: reduce l across the 4 k-slot lanes, then normalize + store
#pragma unroll
  for (int qs = 0; qs < 2; qs++) {
    float l = lp[qs];
    l += __shfl_xor(l, 16);
    l += __shfl_xor(l, 32);
    float rl = 1.f / l;
    int q = qbase + qs * 16 + l15;
    size_t rbase = ((size_t)hb * 2048 + q) * 64;
#pragma unroll
    for (int nd = 0; nd < 4; nd++) {
      ushort4v ov;
#pragma unroll
      for (int j = 0; j < 4; j++) ov[j] = f2bf(o[qs][nd][j] * rl);
      *(ushort4v*)&att[rbase + nd * 16 + l4 * 4] = ov;
    }
  }
}

// ---------------- launch ----------------

extern "C" void kernel_launch(void* const* d_in, const int* in_sizes, int n_in,
                              void* d_out, int out_size, void* d_ws, size_t ws_size,
                              hipStream_t stream) {
  const float* x  = (const float*)d_in[0];
  const float* Wq = (const float*)d_in[1];
  const float* Wk = (const float*)d_in[2];
  const float* Wv = (const float*)d_in[3];
  const float* pw = (const float*)d_in[4];
  const float* pb = (const float*)d_in[5];
  float* out = (float*)d_out;

  char* ws = (char*)d_ws;
  u16* Xb   = (u16*)(ws);                       // 16 MB (dead after GEMM1)
  u16* VTg  = (u16*)(ws);                       // 16 MB (overlays Xb)
  u16* Wcat = (u16*)(ws + (16u << 20));         // 6 MB
  u16* PWt  = (u16*)(ws + (22u << 20));         // 2 MB
  u16* QKV  = (u16*)(ws + (24u << 20));         // 48 MB
  u16* ATT  = (u16*)(ws + (72u << 20));         // 16 MB (total 88 MB)

  prep_kernel<<<9984, 256, 0, stream>>>(x, Wq, Wk, Wv, pw, Xb, Wcat, PWt);

  gemm3b<1><<<768, 512, 0, stream>>>(Xb, Wcat, QKV, nullptr, 8192, 3072, 1024, 64, 1024);

  vt_build<<<2048, 256, 0, stream>>>(QKV, VTg);

  attn_kernel<<<1024, 256, 0, stream>>>(QKV, VTg, ATT);

  gemm3b<0><<<256, 512, 0, stream>>>(ATT, PWt, out, pb, 8192, 1024, 1024, 64, 0);
}

// Round 8
// 195.271 us; speedup vs baseline: 1.6667x; 1.6667x over previous
//
#include <hip/hip_runtime.h>

typedef unsigned short u16;
typedef __attribute__((ext_vector_type(8))) __bf16 bf16x8;
typedef __attribute__((ext_vector_type(8))) short short8;
typedef __attribute__((ext_vector_type(4))) float f32x4;
typedef __attribute__((ext_vector_type(4))) unsigned short ushort4v;

__device__ __forceinline__ u16 f2bf(float f) {
  unsigned u = __builtin_bit_cast(unsigned, f);
  u += 0x7fffu + ((u >> 16) & 1u);
  return (u16)(u >> 16);
}

__device__ __forceinline__ float exp2_hw(float x) {
  float r; asm("v_exp_f32 %0, %1" : "=v"(r) : "v"(x)); return r;
}
__device__ __forceinline__ unsigned cvt_pk_bf16(float a, float b) {
  unsigned r; asm("v_cvt_pk_bf16_f32 %0, %1, %2" : "=v"(r) : "v"(a), "v"(b)); return r;
}

__device__ __forceinline__ void gload_lds16(const void* g, void* l) {
  __builtin_amdgcn_global_load_lds(
      (__attribute__((address_space(1))) void*)g,
      (__attribute__((address_space(3))) void*)l, 16, 0, 0);
}

__device__ __forceinline__ void BAR() {
  asm volatile("" ::: "memory");
  __builtin_amdgcn_s_barrier();
  asm volatile("" ::: "memory");
}

#define MFMA16(a, b, c) __builtin_amdgcn_mfma_f32_16x16x32_bf16(a, b, c, 0, 0, 0)

// scale folded into Q at GEMM1 epilogue: 1/sqrt(64) * log2(e)
#define QSCALE 0.1803368801111204f

// ---------------- merged prep kernel ----------------

__global__ __launch_bounds__(256)
void prep_kernel(const float* __restrict__ x, const float* __restrict__ Wq,
                 const float* __restrict__ Wk, const float* __restrict__ Wv,
                 const float* __restrict__ pw, u16* __restrict__ Xb,
                 u16* __restrict__ Wcat, u16* __restrict__ PWt) {
  const int b = blockIdx.x, tid = threadIdx.x;
  if (b < 8192) {
    int i = b * 256 + tid;
    float4 v = ((const float4*)x)[i];
    union { u16 u[4]; uint2 v2; } r;
    r.u[0] = f2bf(v.x); r.u[1] = f2bf(v.y); r.u[2] = f2bf(v.z); r.u[3] = f2bf(v.w);
    ((uint2*)Xb)[i] = r.v2;
  } else if (b < 8960) {
    __shared__ u16 lds[64 * 68];
    int bb = b - 8192;
    int sel = bb >> 8, rem = bb & 255;
    int h = rem >> 4, e0 = (rem & 15) * 64;
    const float* W = (sel == 0) ? Wq : (sel == 1) ? Wk : Wv;
    const float* src = W + ((size_t)h * 1024 + e0) * 64;
#pragma unroll
    for (int i = 0; i < 4; i++) {
      int idx = i * 1024 + tid * 4;
      int e = idx >> 6, hs = idx & 63;
      float4 v = *(const float4*)&src[idx];
      u16* d = &lds[e * 68 + hs];
      d[0] = f2bf(v.x); d[1] = f2bf(v.y); d[2] = f2bf(v.z); d[3] = f2bf(v.w);
    }
    __syncthreads();
#pragma unroll
    for (int i = 0; i < 2; i++) {
      int u = i * 256 + tid;
      int hs = u >> 3, ec = u & 7;
      union { u16 q[8]; uint4 v; } ou;
#pragma unroll
      for (int e = 0; e < 8; e++) ou.q[e] = lds[(ec * 8 + e) * 68 + hs];
      size_t n = (size_t)sel * 1024 + h * 64 + hs;
      *(uint4*)&Wcat[n * 1024 + e0 + ec * 8] = ou.v;
    }
  } else {
    int i = (b - 8960) * 256 + tid;
    float4 v = ((const float4*)pw)[i];
    union { u16 u[4]; uint2 v2; } r;
    r.u[0] = f2bf(v.x); r.u[1] = f2bf(v.y); r.u[2] = f2bf(v.z); r.u[3] = f2bf(v.w);
    ((uint2*)PWt)[i] = r.v2;
  }
}

// ---------------- triple-buffered 128x256 GEMM: C = A[M,K] * BT[N,K]^T ----

template<int OUT_BF16>
__global__ __launch_bounds__(512, 2)
void gemm3b(const u16* __restrict__ A, const u16* __restrict__ BT,
            void* __restrict__ Cout, const float* __restrict__ bias,
            int M, int N, int K, int gy, int qcols) {
  __shared__ u16 a_lds[3][128 * 64];
  __shared__ u16 b_lds[3][256 * 64];
  const int nwg = gridDim.x;
  const int qch = nwg >> 3;
  const int wg = (blockIdx.x & 7) * qch + (blockIdx.x >> 3);
  const int bx = wg / gy, by = wg % gy;
  const int tid = threadIdx.x;
  const int lane = tid & 63;
  const int w = tid >> 6;
  const int wr = w >> 2, wc = w & 3;
  const int mBase = by * 128, nBase = bx * 256;
  const int l15 = lane & 15, l4 = lane >> 4;
  const int nkt = K >> 6;

  f32x4 acc[4][4] = {};

  auto STAGE_A = [&](int s, int kt) {
#pragma unroll
    for (int j = 0; j < 2; j++) {
      int e = j * 4096 + tid * 8;
      int row = e >> 6;
      int c = ((e >> 3) & 7) ^ (row & 7);
      gload_lds16(A + (size_t)(mBase + row) * K + kt * 64 + c * 8, &a_lds[s][e]);
    }
  };
  auto STAGE_B = [&](int s, int kt) {
#pragma unroll
    for (int j = 0; j < 4; j++) {
      int e = j * 4096 + tid * 8;
      int row = e >> 6;
      int c = ((e >> 3) & 7) ^ (row & 7);
      gload_lds16(BT + (size_t)(nBase + row) * K + kt * 64 + c * 8, &b_lds[s][e]);
    }
  };

  STAGE_A(0, 0); STAGE_B(0, 0);
  STAGE_A(1, 1); STAGE_B(1, 1);
  asm volatile("s_waitcnt vmcnt(6)" ::: "memory");
  BAR();

  int s0 = 0, s1 = 1, s2 = 2;
  for (int t = 0; t < nkt; t++) {
    const int t2 = (t + 2 < nkt) ? t + 2 : t + 2 - nkt;
    bf16x8 AF[4][2], BF[2][2];

#pragma unroll
    for (int m = 0; m < 4; m++) {
      int row = wr * 64 + m * 16 + l15;
#pragma unroll
      for (int ks = 0; ks < 2; ks++) {
        int ch = (ks * 4 + l4) ^ (row & 7);
        AF[m][ks] = *(const bf16x8*)&a_lds[s0][row * 64 + ch * 8];
      }
    }
#pragma unroll
    for (int n = 0; n < 2; n++) {
      int row = wc * 64 + n * 16 + l15;
#pragma unroll
      for (int ks = 0; ks < 2; ks++) {
        int ch = (ks * 4 + l4) ^ (row & 7);
        BF[n][ks] = *(const bf16x8*)&b_lds[s0][row * 64 + ch * 8];
      }
    }
    STAGE_A(s2, t2);
    STAGE_B(s2, t2);
    __builtin_amdgcn_s_setprio(1);
#pragma unroll
    for (int m = 0; m < 4; m++)
#pragma unroll
      for (int n = 0; n < 2; n++) {
        acc[m][n] = MFMA16(AF[m][0], BF[n][0], acc[m][n]);
        acc[m][n] = MFMA16(AF[m][1], BF[n][1], acc[m][n]);
      }
    __builtin_amdgcn_s_setprio(0);

#pragma unroll
    for (int n = 0; n < 2; n++) {
      int row = wc * 64 + 32 + n * 16 + l15;
#pragma unroll
      for (int ks = 0; ks < 2; ks++) {
        int ch = (ks * 4 + l4) ^ (row & 7);
        BF[n][ks] = *(const bf16x8*)&b_lds[s0][row * 64 + ch * 8];
      }
    }
    __builtin_amdgcn_s_setprio(1);
#pragma unroll
    for (int m = 0; m < 4; m++)
#pragma unroll
      for (int n = 0; n < 2; n++) {
        acc[m][2 + n] = MFMA16(AF[m][0], BF[n][0], acc[m][2 + n]);
        acc[m][2 + n] = MFMA16(AF[m][1], BF[n][1], acc[m][2 + n]);
      }
    __builtin_amdgcn_s_setprio(0);

    asm volatile("s_waitcnt vmcnt(6)" ::: "memory");
    BAR();
    int tmp = s0; s0 = s1; s1 = s2; s2 = tmp;
  }

#pragma unroll
  for (int mi = 0; mi < 4; mi++) {
    int row = mBase + wr * 64 + mi * 16 + l4 * 4;
#pragma unroll
    for (int ni = 0; ni < 4; ni++) {
      int col = nBase + wc * 64 + ni * 16 + l15;
      float scl = (col < qcols) ? QSCALE : 1.f;
#pragma unroll
      for (int j = 0; j < 4; j++) {
        float v = acc[mi][ni][j];
        if (OUT_BF16) {
          ((u16*)Cout)[(size_t)(row + j) * N + col] = f2bf(v * scl);
        } else {
          ((float*)Cout)[(size_t)(row + j) * N + col] = v + bias[col];
        }
      }
    }
  }
}

// ---------------- V transpose: VT[hb][d][t] from QKV V-section ----------------

__global__ __launch_bounds__(256)
void vt_build(const u16* __restrict__ qkv, u16* __restrict__ vt) {
  __shared__ u16 lds[64 * 66];
  const int hb = blockIdx.x >> 5, tc = blockIdx.x & 31;
  const int t0 = tc * 64, tid = threadIdx.x;
#pragma unroll
  for (int i = 0; i < 2; i++) {
    int idx = i * 2048 + tid * 8;
    int tl = idx >> 6, d0 = idx & 63;
    int r = hb * 2048 + t0 + tl;
    const u16* src = &qkv[(size_t)(r >> 4) * 3072 + 2048 + (r & 15) * 64 + d0];
    uint4 v = *(const uint4*)src;
    u16* dst = &lds[tl * 66 + d0];
    *(unsigned*)(dst + 0) = v.x; *(unsigned*)(dst + 2) = v.y;
    *(unsigned*)(dst + 4) = v.z; *(unsigned*)(dst + 6) = v.w;
  }
  __syncthreads();
#pragma unroll
  for (int i = 0; i < 2; i++) {
    int idx = i * 2048 + tid * 8;
    int d = idx >> 6, tl0 = idx & 63;
    union { u16 u[8]; uint4 v; } ou;
#pragma unroll
    for (int e = 0; e < 8; e++) ou.u[e] = lds[(tl0 + e) * 66 + d];
    *(uint4*)&vt[(size_t)hb * 131072 + (size_t)d * 2048 + t0 + tl0] = ou.v;
  }
}

// ---------------- flash attention (causal), swapped-operand, no-max softmax --
// 8 waves x 32 q-rows = 256 q-rows per block; KVBLK=64 double-buffered.
// Per-wave P slice in p_lds (wave-private, no extra barrier). l-sum deferred
// to epilogue. Grid: 512 blocks, hb-chunked per XCD, heavy-qb-first (LPT).

__global__ __launch_bounds__(512, 2)
void attn_kernel(const u16* __restrict__ qkv, const u16* __restrict__ vtg,
                 u16* __restrict__ att) {
  __shared__ u16 k_lds[2][64 * 64];
  __shared__ u16 v_lds[2][64 * 64];
  __shared__ u16 p_lds[8][32 * 72];

  const int xcd = blockIdx.x & 7;
  const int c = blockIdx.x >> 3;          // 0..63 within XCD chunk
  const int hb = xcd * 8 + (c & 7);       // hb-contiguous per XCD (K/V L2 reuse)
  const int qb = 7 - (c >> 3);            // heavy blocks first
  const int tid = threadIdx.x;
  const int lane = tid & 63, w = tid >> 6;
  const int l15 = lane & 15, l4 = lane >> 4;
  const int qbase = qb * 256 + w * 32;
  const int nkt = 4 * qb + 4;

  bf16x8 aQ[2][2];
#pragma unroll
  for (int qs = 0; qs < 2; qs++) {
    int t = qbase + qs * 16 + l15;
    int r = hb * 2048 + t;
    size_t base = (size_t)(r >> 4) * 3072 + (r & 15) * 64;
#pragma unroll
    for (int kc = 0; kc < 2; kc++)
      aQ[qs][kc] = *(const bf16x8*)&qkv[base + kc * 32 + l4 * 8];
  }

  f32x4 o[2][4] = {};
  float lp[2] = {0.f, 0.f};   // per-lane partial sums, reduced in epilogue

  auto STAGE = [&](int buf, int kt) {
    {
      int U = tid * 8;
      int row = U >> 6;
      int chunk = ((U >> 3) & 7) ^ (row & 7);
      int rK = hb * 2048 + kt * 64 + row;
      gload_lds16(&qkv[(size_t)(rK >> 4) * 3072 + 1024 + (rK & 15) * 64 + chunk * 8],
                  &k_lds[buf][U]);
    }
    {
      int U = tid * 8;
      int row = U >> 6;
      int chunk = ((U >> 3) & 7) ^ (row & 7);
      gload_lds16(&vtg[(size_t)hb * 131072 + (size_t)row * 2048 + kt * 64 + chunk * 8],
                  &v_lds[buf][U]);
    }
  };

  STAGE(0, 0);
  asm volatile("s_waitcnt vmcnt(0)" ::: "memory");
  BAR();

  for (int kt = 0; kt < nkt; kt++) {
    if (kt + 1 < nkt) STAGE((kt + 1) & 1, kt + 1);
    const int cur = kt & 1;
    const bool active = (kt * 64 <= qbase + 31);
    if (active) {
      f32x4 st[4][2];
      __builtin_amdgcn_s_setprio(1);
#pragma unroll
      for (int n = 0; n < 4; n++) {
        int row = n * 16 + l15;
        int sw = (row & 7) << 3;
        bf16x8 kf0 = *(const bf16x8*)&k_lds[cur][row * 64 + ((0 + l4 * 8) ^ sw)];
        bf16x8 kf1 = *(const bf16x8*)&k_lds[cur][row * 64 + ((32 + l4 * 8) ^ sw)];
#pragma unroll
        for (int qs = 0; qs < 2; qs++) {
          f32x4 a = {0.f, 0.f, 0.f, 0.f};
          a = MFMA16(kf0, aQ[qs][0], a);
          a = MFMA16(kf1, aQ[qs][1], a);
          st[n][qs] = a;
        }
      }
      __builtin_amdgcn_s_setprio(0);
      const bool full = (kt * 64 + 63 <= qbase);
#pragma unroll
      for (int qs = 0; qs < 2; qs++) {
        int q = qbase + qs * 16 + l15;
#pragma unroll
        for (int n = 0; n < 4; n++) {
          float p[4];
#pragma unroll
          for (int j = 0; j < 4; j++) {
            float v = st[n][qs][j];
            if (!full) {
              int k = kt * 64 + n * 16 + l4 * 4 + j;
              v = (k > q) ? -INFINITY : v;
            }
            p[j] = exp2_hw(v);
            lp[qs] += p[j];
          }
          uint2 pk;
          pk.x = cvt_pk_bf16(p[0], p[1]);
          pk.y = cvt_pk_bf16(p[2], p[3]);
          *(uint2*)&p_lds[w][(qs * 16 + l15) * 72 + n * 16 + l4 * 4] = pk;
        }
      }
#pragma unroll
      for (int ks = 0; ks < 2; ks++) {
        bf16x8 pf[2];
#pragma unroll
        for (int qs = 0; qs < 2; qs++)
          pf[qs] = *(const bf16x8*)&p_lds[w][(qs * 16 + l15) * 72 + ks * 32 + l4 * 8];
        __builtin_amdgcn_s_setprio(1);
#pragma unroll
        for (int nd = 0; nd < 4; nd++) {
          int row = nd * 16 + l15;
          int sw = (row & 7) << 3;
          bf16x8 vf = *(const bf16x8*)&v_lds[cur][row * 64 + ((ks * 32 + l4 * 8) ^ sw)];
#pragma unroll
          for (int qs = 0; qs < 2; qs++)
            o[qs][nd] = MFMA16(vf, pf[qs], o[qs][nd]);
        }
        __builtin_amdgcn_s_setprio(0);
      }
    }
    asm volatile("s_waitcnt vmcnt(0)" ::: "memory");
    BAR();
  }

  // epilogue: reduce l across the 4 k-slot lanes, normalize, store
#pragma unroll
  for (int qs = 0; qs < 2; qs++) {
    float l = lp[qs];
    l += __shfl_xor(l, 16);
    l += __shfl_xor(l, 32);
    float rl = 1.f / l;
    int q = qbase + qs * 16 + l15;
    size_t rbase = ((size_t)hb * 2048 + q) * 64;
#pragma unroll
    for (int nd = 0; nd < 4; nd++) {
      ushort4v ov;
#pragma unroll
      for (int j = 0; j < 4; j++) ov[j] = f2bf(o[qs][nd][j] * rl);
      *(ushort4v*)&att[rbase + nd * 16 + l4 * 4] = ov;
    }
  }
}

// ---------------- launch ----------------

extern "C" void kernel_launch(void* const* d_in, const int* in_sizes, int n_in,
                              void* d_out, int out_size, void* d_ws, size_t ws_size,
                              hipStream_t stream) {
  const float* x  = (const float*)d_in[0];
  const float* Wq = (const float*)d_in[1];
  const float* Wk = (const float*)d_in[2];
  const float* Wv = (const float*)d_in[3];
  const float* pw = (const float*)d_in[4];
  const float* pb = (const float*)d_in[5];
  float* out = (float*)d_out;

  char* ws = (char*)d_ws;
  u16* Xb   = (u16*)(ws);                       // 16 MB (dead after GEMM1)
  u16* VTg  = (u16*)(ws);                       // 16 MB (overlays Xb)
  u16* Wcat = (u16*)(ws + (16u << 20));         // 6 MB
  u16* PWt  = (u16*)(ws + (22u << 20));         // 2 MB
  u16* QKV  = (u16*)(ws + (24u << 20));         // 48 MB
  u16* ATT  = (u16*)(ws + (72u << 20));         // 16 MB (total 88 MB)

  prep_kernel<<<9984, 256, 0, stream>>>(x, Wq, Wk, Wv, pw, Xb, Wcat, PWt);

  gemm3b<1><<<768, 512, 0, stream>>>(Xb, Wcat, QKV, nullptr, 8192, 3072, 1024, 64, 1024);

  vt_build<<<2048, 256, 0, stream>>>(QKV, VTg);

  attn_kernel<<<512, 512, 0, stream>>>(QKV, VTg, ATT);

  gemm3b<0><<<256, 512, 0, stream>>>(ATT, PWt, out, pb, 8192, 1024, 1024, 64, 0);
}

// Round 9
// 186.708 us; speedup vs baseline: 1.7431x; 1.0459x over previous
//
#include <hip/hip_runtime.h>

typedef unsigned short u16;
typedef __attribute__((ext_vector_type(8))) __bf16 bf16x8;
typedef __attribute__((ext_vector_type(4))) float f32x4;
typedef __attribute__((ext_vector_type(16))) float f32x16;
typedef __attribute__((ext_vector_type(4))) unsigned short ushort4v;
typedef __attribute__((ext_vector_type(2))) unsigned uint2v;

__device__ __forceinline__ u16 f2bf(float f) {
  unsigned u = __builtin_bit_cast(unsigned, f);
  u += 0x7fffu + ((u >> 16) & 1u);
  return (u16)(u >> 16);
}

__device__ __forceinline__ float exp2_hw(float x) {
  float r; asm("v_exp_f32 %0, %1" : "=v"(r) : "v"(x)); return r;
}
__device__ __forceinline__ unsigned cvt_pk_bf16(float a, float b) {
  unsigned r; asm("v_cvt_pk_bf16_f32 %0, %1, %2" : "=v"(r) : "v"(a), "v"(b)); return r;
}

__device__ __forceinline__ void gload_lds16(const void* g, void* l) {
  __builtin_amdgcn_global_load_lds(
      (__attribute__((address_space(1))) void*)g,
      (__attribute__((address_space(3))) void*)l, 16, 0, 0);
}

__device__ __forceinline__ void BAR() {
  asm volatile("" ::: "memory");
  __builtin_amdgcn_s_barrier();
  asm volatile("" ::: "memory");
}

#define MFMA16(a, b, c) __builtin_amdgcn_mfma_f32_16x16x32_bf16(a, b, c, 0, 0, 0)
#define MFMA32(a, b, c) __builtin_amdgcn_mfma_f32_32x32x16_bf16(a, b, c, 0, 0, 0)

// scale folded into Q at GEMM1 epilogue: 1/sqrt(64) * log2(e)
#define QSCALE 0.1803368801111204f

// ---------------- merged prep kernel ----------------

__global__ __launch_bounds__(256)
void prep_kernel(const float* __restrict__ x, const float* __restrict__ Wq,
                 const float* __restrict__ Wk, const float* __restrict__ Wv,
                 const float* __restrict__ pw, u16* __restrict__ Xb,
                 u16* __restrict__ Wcat, u16* __restrict__ PWt) {
  const int b = blockIdx.x, tid = threadIdx.x;
  if (b < 8192) {
    int i = b * 256 + tid;
    float4 v = ((const float4*)x)[i];
    union { u16 u[4]; uint2 v2; } r;
    r.u[0] = f2bf(v.x); r.u[1] = f2bf(v.y); r.u[2] = f2bf(v.z); r.u[3] = f2bf(v.w);
    ((uint2*)Xb)[i] = r.v2;
  } else if (b < 8960) {
    __shared__ u16 lds[64 * 68];
    int bb = b - 8192;
    int sel = bb >> 8, rem = bb & 255;
    int h = rem >> 4, e0 = (rem & 15) * 64;
    const float* W = (sel == 0) ? Wq : (sel == 1) ? Wk : Wv;
    const float* src = W + ((size_t)h * 1024 + e0) * 64;
#pragma unroll
    for (int i = 0; i < 4; i++) {
      int idx = i * 1024 + tid * 4;
      int e = idx >> 6, hs = idx & 63;
      float4 v = *(const float4*)&src[idx];
      u16* d = &lds[e * 68 + hs];
      d[0] = f2bf(v.x); d[1] = f2bf(v.y); d[2] = f2bf(v.z); d[3] = f2bf(v.w);
    }
    __syncthreads();
#pragma unroll
    for (int i = 0; i < 2; i++) {
      int u = i * 256 + tid;
      int hs = u >> 3, ec = u & 7;
      union { u16 q[8]; uint4 v; } ou;
#pragma unroll
      for (int e = 0; e < 8; e++) ou.q[e] = lds[(ec * 8 + e) * 68 + hs];
      size_t n = (size_t)sel * 1024 + h * 64 + hs;
      *(uint4*)&Wcat[n * 1024 + e0 + ec * 8] = ou.v;
    }
  } else {
    int i = (b - 8960) * 256 + tid;
    float4 v = ((const float4*)pw)[i];
    union { u16 u[4]; uint2 v2; } r;
    r.u[0] = f2bf(v.x); r.u[1] = f2bf(v.y); r.u[2] = f2bf(v.z); r.u[3] = f2bf(v.w);
    ((uint2*)PWt)[i] = r.v2;
  }
}

// ---------------- triple-buffered 128x256 GEMM: C = A[M,K] * BT[N,K]^T ----

template<int OUT_BF16>
__global__ __launch_bounds__(512, 2)
void gemm3b(const u16* __restrict__ A, const u16* __restrict__ BT,
            void* __restrict__ Cout, const float* __restrict__ bias,
            int M, int N, int K, int gy, int qcols) {
  __shared__ u16 a_lds[3][128 * 64];
  __shared__ u16 b_lds[3][256 * 64];
  const int nwg = gridDim.x;
  const int qch = nwg >> 3;
  const int wg = (blockIdx.x & 7) * qch + (blockIdx.x >> 3);
  const int bx = wg / gy, by = wg % gy;
  const int tid = threadIdx.x;
  const int lane = tid & 63;
  const int w = tid >> 6;
  const int wr = w >> 2, wc = w & 3;
  const int mBase = by * 128, nBase = bx * 256;
  const int l15 = lane & 15, l4 = lane >> 4;
  const int nkt = K >> 6;

  f32x4 acc[4][4] = {};

  auto STAGE_A = [&](int s, int kt) {
#pragma unroll
    for (int j = 0; j < 2; j++) {
      int e = j * 4096 + tid * 8;
      int row = e >> 6;
      int c = ((e >> 3) & 7) ^ (row & 7);
      gload_lds16(A + (size_t)(mBase + row) * K + kt * 64 + c * 8, &a_lds[s][e]);
    }
  };
  auto STAGE_B = [&](int s, int kt) {
#pragma unroll
    for (int j = 0; j < 4; j++) {
      int e = j * 4096 + tid * 8;
      int row = e >> 6;
      int c = ((e >> 3) & 7) ^ (row & 7);
      gload_lds16(BT + (size_t)(nBase + row) * K + kt * 64 + c * 8, &b_lds[s][e]);
    }
  };

  STAGE_A(0, 0); STAGE_B(0, 0);
  STAGE_A(1, 1); STAGE_B(1, 1);
  asm volatile("s_waitcnt vmcnt(6)" ::: "memory");
  BAR();

  int s0 = 0, s1 = 1, s2 = 2;
  for (int t = 0; t < nkt; t++) {
    const int t2 = (t + 2 < nkt) ? t + 2 : t + 2 - nkt;
    bf16x8 AF[4][2], BF[2][2];

#pragma unroll
    for (int m = 0; m < 4; m++) {
      int row = wr * 64 + m * 16 + l15;
#pragma unroll
      for (int ks = 0; ks < 2; ks++) {
        int ch = (ks * 4 + l4) ^ (row & 7);
        AF[m][ks] = *(const bf16x8*)&a_lds[s0][row * 64 + ch * 8];
      }
    }
#pragma unroll
    for (int n = 0; n < 2; n++) {
      int row = wc * 64 + n * 16 + l15;
#pragma unroll
      for (int ks = 0; ks < 2; ks++) {
        int ch = (ks * 4 + l4) ^ (row & 7);
        BF[n][ks] = *(const bf16x8*)&b_lds[s0][row * 64 + ch * 8];
      }
    }
    STAGE_A(s2, t2);
    STAGE_B(s2, t2);
    __builtin_amdgcn_s_setprio(1);
#pragma unroll
    for (int m = 0; m < 4; m++)
#pragma unroll
      for (int n = 0; n < 2; n++) {
        acc[m][n] = MFMA16(AF[m][0], BF[n][0], acc[m][n]);
        acc[m][n] = MFMA16(AF[m][1], BF[n][1], acc[m][n]);
      }
    __builtin_amdgcn_s_setprio(0);

#pragma unroll
    for (int n = 0; n < 2; n++) {
      int row = wc * 64 + 32 + n * 16 + l15;
#pragma unroll
      for (int ks = 0; ks < 2; ks++) {
        int ch = (ks * 4 + l4) ^ (row & 7);
        BF[n][ks] = *(const bf16x8*)&b_lds[s0][row * 64 + ch * 8];
      }
    }
    __builtin_amdgcn_s_setprio(1);
#pragma unroll
    for (int m = 0; m < 4; m++)
#pragma unroll
      for (int n = 0; n < 2; n++) {
        acc[m][2 + n] = MFMA16(AF[m][0], BF[n][0], acc[m][2 + n]);
        acc[m][2 + n] = MFMA16(AF[m][1], BF[n][1], acc[m][2 + n]);
      }
    __builtin_amdgcn_s_setprio(0);

    asm volatile("s_waitcnt vmcnt(6)" ::: "memory");
    BAR();
    int tmp = s0; s0 = s1; s1 = s2; s2 = tmp;
  }

#pragma unroll
  for (int mi = 0; mi < 4; mi++) {
    int row = mBase + wr * 64 + mi * 16 + l4 * 4;
#pragma unroll
    for (int ni = 0; ni < 4; ni++) {
      int col = nBase + wc * 64 + ni * 16 + l15;
      float scl = (col < qcols) ? QSCALE : 1.f;
#pragma unroll
      for (int j = 0; j < 4; j++) {
        float v = acc[mi][ni][j];
        if (OUT_BF16) {
          ((u16*)Cout)[(size_t)(row + j) * N + col] = f2bf(v * scl);
        } else {
          ((float*)Cout)[(size_t)(row + j) * N + col] = v + bias[col];
        }
      }
    }
  }
}

// ---------------- V transpose: VT[hb][d][t] from QKV V-section ----------------

__global__ __launch_bounds__(256)
void vt_build(const u16* __restrict__ qkv, u16* __restrict__ vt) {
  __shared__ u16 lds[64 * 66];
  const int hb = blockIdx.x >> 5, tc = blockIdx.x & 31;
  const int t0 = tc * 64, tid = threadIdx.x;
#pragma unroll
  for (int i = 0; i < 2; i++) {
    int idx = i * 2048 + tid * 8;
    int tl = idx >> 6, d0 = idx & 63;
    int r = hb * 2048 + t0 + tl;
    const u16* src = &qkv[(size_t)(r >> 4) * 3072 + 2048 + (r & 15) * 64 + d0];
    uint4 v = *(const uint4*)src;
    u16* dst = &lds[tl * 66 + d0];
    *(unsigned*)(dst + 0) = v.x; *(unsigned*)(dst + 2) = v.y;
    *(unsigned*)(dst + 4) = v.z; *(unsigned*)(dst + 6) = v.w;
  }
  __syncthreads();
#pragma unroll
  for (int i = 0; i < 2; i++) {
    int idx = i * 2048 + tid * 8;
    int d = idx >> 6, tl0 = idx & 63;
    union { u16 u[8]; uint4 v; } ou;
#pragma unroll
    for (int e = 0; e < 8; e++) ou.u[e] = lds[(tl0 + e) * 66 + d];
    *(uint4*)&vt[(size_t)hb * 131072 + (size_t)d * 2048 + t0 + tl0] = ou.v;
  }
}

// ---------------- flash attention (causal), 32x32 MFMA, in-register P ------
// Swapped S^T = mfma32(K, Q): lane owns q = l&31; k rows (r&3)+8*(r>>2)+4*(l>>5).
// P -> PV B-frag entirely in registers via cvt_pk_bf16 + permlane32_swap (T12):
//   swap(pk(p0,p1), pk(p4,p5)) -> words 0,2 ; swap(pk(p2,p3), pk(p6,p7)) -> 1,3.
// No p_lds: LDS = 32 KiB (K/V double-buffered). No-max softmax (exp2 domain,
// scores bounded), one l-reduction in the epilogue.

__global__ __launch_bounds__(512, 4)
void attn_kernel(const u16* __restrict__ qkv, const u16* __restrict__ vtg,
                 u16* __restrict__ att) {
  __shared__ u16 k_lds[2][64 * 64];
  __shared__ u16 v_lds[2][64 * 64];

  const int xcd = blockIdx.x & 7;
  const int c = blockIdx.x >> 3;
  const int hb = xcd * 8 + (c & 7);       // hb-contiguous per XCD
  const int qb = 7 - (c >> 3);            // heavy blocks first
  const int tid = threadIdx.x;
  const int lane = tid & 63, w = tid >> 6;
  const int l31 = lane & 31, l5 = lane >> 5;
  const int qbase = qb * 256 + w * 32;
  const int nkt = 4 * qb + 4;

  // Q B-frags: col q = l31, d = t*16 + l5*8 + i
  bf16x8 qf[4];
  {
    int t = qbase + l31;
    int r = hb * 2048 + t;
    size_t base = (size_t)(r >> 4) * 3072 + (r & 15) * 64;
#pragma unroll
    for (int d = 0; d < 4; d++)
      qf[d] = *(const bf16x8*)&qkv[base + d * 16 + l5 * 8];
  }

  f32x16 o0 = {}, o1 = {};
  float lp = 0.f;

  auto STAGE = [&](int buf, int kt) {
    {
      int U = tid * 8;
      int row = U >> 6;
      int chunk = ((U >> 3) & 7) ^ (row & 7);
      int rK = hb * 2048 + kt * 64 + row;
      gload_lds16(&qkv[(size_t)(rK >> 4) * 3072 + 1024 + (rK & 15) * 64 + chunk * 8],
                  &k_lds[buf][U]);
    }
    {
      int U = tid * 8;
      int row = U >> 6;
      int chunk = ((U >> 3) & 7) ^ (row & 7);
      gload_lds16(&vtg[(size_t)hb * 131072 + (size_t)row * 2048 + kt * 64 + chunk * 8],
                  &v_lds[buf][U]);
    }
  };

  STAGE(0, 0);
  asm volatile("s_waitcnt vmcnt(0)" ::: "memory");
  BAR();

  for (int kt = 0; kt < nkt; kt++) {
    if (kt + 1 < nkt) STAGE((kt + 1) & 1, kt + 1);
    const int cur = kt & 1;
    const bool active = (kt * 64 <= qbase + 31);
    if (active) {
      const bool full = (kt * 64 + 63 <= qbase);
      const int q = qbase + l31;
#pragma unroll
      for (int kb = 0; kb < 2; kb++) {
        // QK: S^T[k = kt*64+kb*32+pattern][q = l31]
        int krow = kb * 32 + l31;
        int ksw = krow & 7;
        f32x16 st = {};
        __builtin_amdgcn_s_setprio(1);
#pragma unroll
        for (int t = 0; t < 4; t++) {
          bf16x8 kf = *(const bf16x8*)&k_lds[cur][krow * 64 + ((t * 2 + l5) ^ ksw) * 8];
          st = MFMA32(kf, qf[t], st);
        }
        __builtin_amdgcn_s_setprio(0);
        // mask + exp2
        float p[16];
#pragma unroll
        for (int r = 0; r < 16; r++) {
          float v = st[r];
          if (!full) {
            int k = kt * 64 + kb * 32 + (r & 3) + 8 * (r >> 2) + 4 * l5;
            v = (k > q) ? -INFINITY : v;
          }
          p[r] = exp2_hw(v);
          lp += p[r];
        }
        // pack + permlane -> PV B-frags, then PV MFMA
#pragma unroll
        for (int kc = 0; kc < 2; kc++) {
          unsigned w0 = cvt_pk_bf16(p[kc * 8 + 0], p[kc * 8 + 1]);
          unsigned w1 = cvt_pk_bf16(p[kc * 8 + 2], p[kc * 8 + 3]);
          unsigned w2 = cvt_pk_bf16(p[kc * 8 + 4], p[kc * 8 + 5]);
          unsigned w3 = cvt_pk_bf16(p[kc * 8 + 6], p[kc * 8 + 7]);
          uint2v s0 = __builtin_amdgcn_permlane32_swap(w0, w2, false, false);
          uint2v s1 = __builtin_amdgcn_permlane32_swap(w1, w3, false, false);
          union { unsigned u[4]; bf16x8 v; } pf;
          pf.u[0] = s0.x; pf.u[1] = s1.x; pf.u[2] = s0.y; pf.u[3] = s1.y;
          __builtin_amdgcn_s_setprio(1);
          {
            int row0 = l31;
            int ch0 = (kb * 4 + kc * 2 + l5) ^ (row0 & 7);
            bf16x8 vf0 = *(const bf16x8*)&v_lds[cur][row0 * 64 + ch0 * 8];
            o0 = MFMA32(vf0, pf.v, o0);
            int row1 = 32 + l31;
            int ch1 = (kb * 4 + kc * 2 + l5) ^ (row1 & 7);
            bf16x8 vf1 = *(const bf16x8*)&v_lds[cur][row1 * 64 + ch1 * 8];
            o1 = MFMA32(vf1, pf.v, o1);
          }
          __builtin_amdgcn_s_setprio(0);
        }
      }
    }
    asm volatile("s_waitcnt vmcnt(0)" ::: "memory");
    BAR();
  }

  // epilogue: combine the two k-half partial sums, normalize, store O^T
  lp += __shfl_xor(lp, 32);
  float rl = 1.f / lp;
  {
    int q = qbase + l31;
    size_t rbase = ((size_t)hb * 2048 + q) * 64;
#pragma unroll
    for (int g = 0; g < 4; g++) {
      uint2 wv;
      wv.x = cvt_pk_bf16(o0[4 * g + 0] * rl, o0[4 * g + 1] * rl);
      wv.y = cvt_pk_bf16(o0[4 * g + 2] * rl, o0[4 * g + 3] * rl);
      *(uint2*)&att[rbase + g * 8 + 4 * l5] = wv;
      uint2 wu;
      wu.x = cvt_pk_bf16(o1[4 * g + 0] * rl, o1[4 * g + 1] * rl);
      wu.y = cvt_pk_bf16(o1[4 * g + 2] * rl, o1[4 * g + 3] * rl);
      *(uint2*)&att[rbase + 32 + g * 8 + 4 * l5] = wu;
    }
  }
}

// ---------------- launch ----------------

extern "C" void kernel_launch(void* const* d_in, const int* in_sizes, int n_in,
                              void* d_out, int out_size, void* d_ws, size_t ws_size,
                              hipStream_t stream) {
  const float* x  = (const float*)d_in[0];
  const float* Wq = (const float*)d_in[1];
  const float* Wk = (const float*)d_in[2];
  const float* Wv = (const float*)d_in[3];
  const float* pw = (const float*)d_in[4];
  const float* pb = (const float*)d_in[5];
  float* out = (float*)d_out;

  char* ws = (char*)d_ws;
  u16* Xb   = (u16*)(ws);                       // 16 MB (dead after GEMM1)
  u16* VTg  = (u16*)(ws);                       // 16 MB (overlays Xb)
  u16* Wcat = (u16*)(ws + (16u << 20));         // 6 MB
  u16* PWt  = (u16*)(ws + (22u << 20));         // 2 MB
  u16* QKV  = (u16*)(ws + (24u << 20));         // 48 MB
  u16* ATT  = (u16*)(ws + (72u << 20));         // 16 MB (total 88 MB)

  prep_kernel<<<9984, 256, 0, stream>>>(x, Wq, Wk, Wv, pw, Xb, Wcat, PWt);

  gemm3b<1><<<768, 512, 0, stream>>>(Xb, Wcat, QKV, nullptr, 8192, 3072, 1024, 64, 1024);

  vt_build<<<2048, 256, 0, stream>>>(QKV, VTg);

  attn_kernel<<<512, 512, 0, stream>>>(QKV, VTg, ATT);

  gemm3b<0><<<256, 512, 0, stream>>>(ATT, PWt, out, pb, 8192, 1024, 1024, 64, 0);
}

// Round 10
// 166.606 us; speedup vs baseline: 1.9534x; 1.1207x over previous
//
#include <hip/hip_runtime.h>

typedef unsigned short u16;
typedef __attribute__((ext_vector_type(8))) __bf16 bf16x8;
typedef __attribute__((ext_vector_type(4))) float f32x4;
typedef __attribute__((ext_vector_type(16))) float f32x16;
typedef __attribute__((ext_vector_type(4))) unsigned short ushort4v;
typedef __attribute__((ext_vector_type(2))) unsigned uint2v;

__device__ __forceinline__ u16 f2bf(float f) {
  unsigned u = __builtin_bit_cast(unsigned, f);
  u += 0x7fffu + ((u >> 16) & 1u);
  return (u16)(u >> 16);
}

__device__ __forceinline__ float exp2_hw(float x) {
  float r; asm("v_exp_f32 %0, %1" : "=v"(r) : "v"(x)); return r;
}
__device__ __forceinline__ unsigned cvt_pk_bf16(float a, float b) {
  unsigned r; asm("v_cvt_pk_bf16_f32 %0, %1, %2" : "=v"(r) : "v"(a), "v"(b)); return r;
}

__device__ __forceinline__ void gload_lds16(const void* g, void* l) {
  __builtin_amdgcn_global_load_lds(
      (__attribute__((address_space(1))) void*)g,
      (__attribute__((address_space(3))) void*)l, 16, 0, 0);
}

__device__ __forceinline__ void BAR() {
  asm volatile("" ::: "memory");
  __builtin_amdgcn_s_barrier();
  asm volatile("" ::: "memory");
}

#define MFMA16(a, b, c) __builtin_amdgcn_mfma_f32_16x16x32_bf16(a, b, c, 0, 0, 0)
#define MFMA32(a, b, c) __builtin_amdgcn_mfma_f32_32x32x16_bf16(a, b, c, 0, 0, 0)

// scale folded into Q at GEMM1 epilogue: 1/sqrt(64) * log2(e)
#define QSCALE 0.1803368801111204f

// ---------------- merged prep kernel ----------------

__global__ __launch_bounds__(256)
void prep_kernel(const float* __restrict__ x, const float* __restrict__ Wq,
                 const float* __restrict__ Wk, const float* __restrict__ Wv,
                 const float* __restrict__ pw, u16* __restrict__ Xb,
                 u16* __restrict__ Wcat, u16* __restrict__ PWt) {
  const int b = blockIdx.x, tid = threadIdx.x;
  if (b < 8192) {
    int i = b * 256 + tid;
    float4 v = ((const float4*)x)[i];
    union { u16 u[4]; uint2 v2; } r;
    r.u[0] = f2bf(v.x); r.u[1] = f2bf(v.y); r.u[2] = f2bf(v.z); r.u[3] = f2bf(v.w);
    ((uint2*)Xb)[i] = r.v2;
  } else if (b < 8960) {
    __shared__ u16 lds[64 * 68];
    int bb = b - 8192;
    int sel = bb >> 8, rem = bb & 255;
    int h = rem >> 4, e0 = (rem & 15) * 64;
    const float* W = (sel == 0) ? Wq : (sel == 1) ? Wk : Wv;
    const float* src = W + ((size_t)h * 1024 + e0) * 64;
#pragma unroll
    for (int i = 0; i < 4; i++) {
      int idx = i * 1024 + tid * 4;
      int e = idx >> 6, hs = idx & 63;
      float4 v = *(const float4*)&src[idx];
      u16* d = &lds[e * 68 + hs];
      d[0] = f2bf(v.x); d[1] = f2bf(v.y); d[2] = f2bf(v.z); d[3] = f2bf(v.w);
    }
    __syncthreads();
#pragma unroll
    for (int i = 0; i < 2; i++) {
      int u = i * 256 + tid;
      int hs = u >> 3, ec = u & 7;
      union { u16 q[8]; uint4 v; } ou;
#pragma unroll
      for (int e = 0; e < 8; e++) ou.q[e] = lds[(ec * 8 + e) * 68 + hs];
      size_t n = (size_t)sel * 1024 + h * 64 + hs;
      *(uint4*)&Wcat[n * 1024 + e0 + ec * 8] = ou.v;
    }
  } else {
    int i = (b - 8960) * 256 + tid;
    float4 v = ((const float4*)pw)[i];
    union { u16 u[4]; uint2 v2; } r;
    r.u[0] = f2bf(v.x); r.u[1] = f2bf(v.y); r.u[2] = f2bf(v.z); r.u[3] = f2bf(v.w);
    ((uint2*)PWt)[i] = r.v2;
  }
}

// ---------------- triple-buffered 128x256 GEMM, 2 sub-phases per K-tile ----
// L2 remap: each XCD owns an 8-M-block chunk (2 MB of A, L2-resident),
// iterates N-panels M-fastest. Staging always targets the never-read third
// buffer (race-free), so sub-phase barriers are safe; vmcnt(6) never drains.

template<int OUT_BF16>
__global__ __launch_bounds__(512, 2)
void gemm3b(const u16* __restrict__ A, const u16* __restrict__ BT,
            void* __restrict__ Cout, const float* __restrict__ bias,
            int M, int N, int K, int qcols) {
  __shared__ u16 a_lds[3][128 * 64];
  __shared__ u16 b_lds[3][256 * 64];
  const int xcd = blockIdx.x & 7;
  const int local = blockIdx.x >> 3;
  const int by = xcd * 8 + (local & 7);   // M-chunk of 8 blocks per XCD
  const int bx = local >> 3;              // N-panel, slow
  const int tid = threadIdx.x;
  const int lane = tid & 63;
  const int w = tid >> 6;
  const int wr = w >> 2, wc = w & 3;
  const int mBase = by * 128, nBase = bx * 256;
  const int l15 = lane & 15, l4 = lane >> 4;
  const int nkt = K >> 6;

  f32x4 acc[4][4] = {};

  auto STAGE_A = [&](int s, int kt) {
#pragma unroll
    for (int j = 0; j < 2; j++) {
      int e = j * 4096 + tid * 8;
      int row = e >> 6;
      int c = ((e >> 3) & 7) ^ (row & 7);
      gload_lds16(A + (size_t)(mBase + row) * K + kt * 64 + c * 8, &a_lds[s][e]);
    }
  };
  auto STAGE_B = [&](int s, int kt) {
#pragma unroll
    for (int j = 0; j < 4; j++) {
      int e = j * 4096 + tid * 8;
      int row = e >> 6;
      int c = ((e >> 3) & 7) ^ (row & 7);
      gload_lds16(BT + (size_t)(nBase + row) * K + kt * 64 + c * 8, &b_lds[s][e]);
    }
  };

  STAGE_A(0, 0); STAGE_B(0, 0);
  STAGE_A(1, 1); STAGE_B(1, 1);
  asm volatile("s_waitcnt vmcnt(6)" ::: "memory");
  BAR();

  int s0 = 0, s1 = 1, s2 = 2;
  for (int t = 0; t < nkt; t++) {
    const int t2 = (t + 2 < nkt) ? t + 2 : t + 2 - nkt;
    bf16x8 AF[4][2], BF[2][2];

    // ---- sub-phase A: read AF + BF0, issue A-stage, compute acc[.][0..1] ----
#pragma unroll
    for (int m = 0; m < 4; m++) {
      int row = wr * 64 + m * 16 + l15;
#pragma unroll
      for (int ks = 0; ks < 2; ks++) {
        int ch = (ks * 4 + l4) ^ (row & 7);
        AF[m][ks] = *(const bf16x8*)&a_lds[s0][row * 64 + ch * 8];
      }
    }
#pragma unroll
    for (int n = 0; n < 2; n++) {
      int row = wc * 64 + n * 16 + l15;
#pragma unroll
      for (int ks = 0; ks < 2; ks++) {
        int ch = (ks * 4 + l4) ^ (row & 7);
        BF[n][ks] = *(const bf16x8*)&b_lds[s0][row * 64 + ch * 8];
      }
    }
    STAGE_A(s2, t2);
    BAR();
    __builtin_amdgcn_s_setprio(1);
#pragma unroll
    for (int m = 0; m < 4; m++)
#pragma unroll
      for (int n = 0; n < 2; n++) {
        acc[m][n] = MFMA16(AF[m][0], BF[n][0], acc[m][n]);
        acc[m][n] = MFMA16(AF[m][1], BF[n][1], acc[m][n]);
      }
    __builtin_amdgcn_s_setprio(0);

    // ---- sub-phase B: read BF1, issue B-stage, compute acc[.][2..3] ----
#pragma unroll
    for (int n = 0; n < 2; n++) {
      int row = wc * 64 + 32 + n * 16 + l15;
#pragma unroll
      for (int ks = 0; ks < 2; ks++) {
        int ch = (ks * 4 + l4) ^ (row & 7);
        BF[n][ks] = *(const bf16x8*)&b_lds[s0][row * 64 + ch * 8];
      }
    }
    STAGE_B(s2, t2);
    BAR();
    __builtin_amdgcn_s_setprio(1);
#pragma unroll
    for (int m = 0; m < 4; m++)
#pragma unroll
      for (int n = 0; n < 2; n++) {
        acc[m][2 + n] = MFMA16(AF[m][0], BF[n][0], acc[m][2 + n]);
        acc[m][2 + n] = MFMA16(AF[m][1], BF[n][1], acc[m][2 + n]);
      }
    __builtin_amdgcn_s_setprio(0);

    // K-tile boundary: t+2's 6 loads in flight; t+1's proven landed.
    asm volatile("s_waitcnt vmcnt(6)" ::: "memory");
    BAR();
    int tmp = s0; s0 = s1; s1 = s2; s2 = tmp;
  }

#pragma unroll
  for (int mi = 0; mi < 4; mi++) {
    int row = mBase + wr * 64 + mi * 16 + l4 * 4;
#pragma unroll
    for (int ni = 0; ni < 4; ni++) {
      int col = nBase + wc * 64 + ni * 16 + l15;
      float scl = (col < qcols) ? QSCALE : 1.f;
#pragma unroll
      for (int j = 0; j < 4; j++) {
        float v = acc[mi][ni][j];
        if (OUT_BF16) {
          ((u16*)Cout)[(size_t)(row + j) * N + col] = f2bf(v * scl);
        } else {
          ((float*)Cout)[(size_t)(row + j) * N + col] = v + bias[col];
        }
      }
    }
  }
}

// ---------------- V transpose: VT[hb][d][t] from QKV V-section ----------------

__global__ __launch_bounds__(256)
void vt_build(const u16* __restrict__ qkv, u16* __restrict__ vt) {
  __shared__ u16 lds[64 * 66];
  const int hb = blockIdx.x >> 5, tc = blockIdx.x & 31;
  const int t0 = tc * 64, tid = threadIdx.x;
#pragma unroll
  for (int i = 0; i < 2; i++) {
    int idx = i * 2048 + tid * 8;
    int tl = idx >> 6, d0 = idx & 63;
    int r = hb * 2048 + t0 + tl;
    const u16* src = &qkv[(size_t)(r >> 4) * 3072 + 2048 + (r & 15) * 64 + d0];
    uint4 v = *(const uint4*)src;
    u16* dst = &lds[tl * 66 + d0];
    *(unsigned*)(dst + 0) = v.x; *(unsigned*)(dst + 2) = v.y;
    *(unsigned*)(dst + 4) = v.z; *(unsigned*)(dst + 6) = v.w;
  }
  __syncthreads();
#pragma unroll
  for (int i = 0; i < 2; i++) {
    int idx = i * 2048 + tid * 8;
    int d = idx >> 6, tl0 = idx & 63;
    union { u16 u[8]; uint4 v; } ou;
#pragma unroll
    for (int e = 0; e < 8; e++) ou.u[e] = lds[(tl0 + e) * 66 + d];
    *(uint4*)&vt[(size_t)hb * 131072 + (size_t)d * 2048 + t0 + tl0] = ou.v;
  }
}

// ---------------- flash attention (causal), 32x32 MFMA, in-register P ------

__global__ __launch_bounds__(512, 4)
void attn_kernel(const u16* __restrict__ qkv, const u16* __restrict__ vtg,
                 u16* __restrict__ att) {
  __shared__ u16 k_lds[2][64 * 64];
  __shared__ u16 v_lds[2][64 * 64];

  const int xcd = blockIdx.x & 7;
  const int c = blockIdx.x >> 3;
  const int hb = xcd * 8 + (c & 7);
  const int qb = 7 - (c >> 3);
  const int tid = threadIdx.x;
  const int lane = tid & 63, w = tid >> 6;
  const int l31 = lane & 31, l5 = lane >> 5;
  const int qbase = qb * 256 + w * 32;
  const int nkt = 4 * qb + 4;

  bf16x8 qf[4];
  {
    int t = qbase + l31;
    int r = hb * 2048 + t;
    size_t base = (size_t)(r >> 4) * 3072 + (r & 15) * 64;
#pragma unroll
    for (int d = 0; d < 4; d++)
      qf[d] = *(const bf16x8*)&qkv[base + d * 16 + l5 * 8];
  }

  f32x16 o0 = {}, o1 = {};
  float lp = 0.f;

  auto STAGE = [&](int buf, int kt) {
    {
      int U = tid * 8;
      int row = U >> 6;
      int chunk = ((U >> 3) & 7) ^ (row & 7);
      int rK = hb * 2048 + kt * 64 + row;
      gload_lds16(&qkv[(size_t)(rK >> 4) * 3072 + 1024 + (rK & 15) * 64 + chunk * 8],
                  &k_lds[buf][U]);
    }
    {
      int U = tid * 8;
      int row = U >> 6;
      int chunk = ((U >> 3) & 7) ^ (row & 7);
      gload_lds16(&vtg[(size_t)hb * 131072 + (size_t)row * 2048 + kt * 64 + chunk * 8],
                  &v_lds[buf][U]);
    }
  };

  STAGE(0, 0);
  asm volatile("s_waitcnt vmcnt(0)" ::: "memory");
  BAR();

  for (int kt = 0; kt < nkt; kt++) {
    if (kt + 1 < nkt) STAGE((kt + 1) & 1, kt + 1);
    const int cur = kt & 1;
    const bool active = (kt * 64 <= qbase + 31);
    if (active) {
      const bool full = (kt * 64 + 63 <= qbase);
      const int q = qbase + l31;
#pragma unroll
      for (int kb = 0; kb < 2; kb++) {
        int krow = kb * 32 + l31;
        int ksw = krow & 7;
        f32x16 st = {};
        __builtin_amdgcn_s_setprio(1);
#pragma unroll
        for (int t = 0; t < 4; t++) {
          bf16x8 kf = *(const bf16x8*)&k_lds[cur][krow * 64 + ((t * 2 + l5) ^ ksw) * 8];
          st = MFMA32(kf, qf[t], st);
        }
        __builtin_amdgcn_s_setprio(0);
        float p[16];
#pragma unroll
        for (int r = 0; r < 16; r++) {
          float v = st[r];
          if (!full) {
            int k = kt * 64 + kb * 32 + (r & 3) + 8 * (r >> 2) + 4 * l5;
            v = (k > q) ? -INFINITY : v;
          }
          p[r] = exp2_hw(v);
          lp += p[r];
        }
#pragma unroll
        for (int kc = 0; kc < 2; kc++) {
          unsigned w0 = cvt_pk_bf16(p[kc * 8 + 0], p[kc * 8 + 1]);
          unsigned w1 = cvt_pk_bf16(p[kc * 8 + 2], p[kc * 8 + 3]);
          unsigned w2 = cvt_pk_bf16(p[kc * 8 + 4], p[kc * 8 + 5]);
          unsigned w3 = cvt_pk_bf16(p[kc * 8 + 6], p[kc * 8 + 7]);
          uint2v s0 = __builtin_amdgcn_permlane32_swap(w0, w2, false, false);
          uint2v s1 = __builtin_amdgcn_permlane32_swap(w1, w3, false, false);
          union { unsigned u[4]; bf16x8 v; } pf;
          pf.u[0] = s0.x; pf.u[1] = s1.x; pf.u[2] = s0.y; pf.u[3] = s1.y;
          __builtin_amdgcn_s_setprio(1);
          {
            int row0 = l31;
            int ch0 = (kb * 4 + kc * 2 + l5) ^ (row0 & 7);
            bf16x8 vf0 = *(const bf16x8*)&v_lds[cur][row0 * 64 + ch0 * 8];
            o0 = MFMA32(vf0, pf.v, o0);
            int row1 = 32 + l31;
            int ch1 = (kb * 4 + kc * 2 + l5) ^ (row1 & 7);
            bf16x8 vf1 = *(const bf16x8*)&v_lds[cur][row1 * 64 + ch1 * 8];
            o1 = MFMA32(vf1, pf.v, o1);
          }
          __builtin_amdgcn_s_setprio(0);
        }
      }
    }
    asm volatile("s_waitcnt vmcnt(0)" ::: "memory");
    BAR();
  }

  lp += __shfl_xor(lp, 32);
  float rl = 1.f / lp;
  {
    int q = qbase + l31;
    size_t rbase = ((size_t)hb * 2048 + q) * 64;
#pragma unroll
    for (int g = 0; g < 4; g++) {
      uint2 wv;
      wv.x = cvt_pk_bf16(o0[4 * g + 0] * rl, o0[4 * g + 1] * rl);
      wv.y = cvt_pk_bf16(o0[4 * g + 2] * rl, o0[4 * g + 3] * rl);
      *(uint2*)&att[rbase + g * 8 + 4 * l5] = wv;
      uint2 wu;
      wu.x = cvt_pk_bf16(o1[4 * g + 0] * rl, o1[4 * g + 1] * rl);
      wu.y = cvt_pk_bf16(o1[4 * g + 2] * rl, o1[4 * g + 3] * rl);
      *(uint2*)&att[rbase + 32 + g * 8 + 4 * l5] = wu;
    }
  }
}

// ---------------- launch ----------------

extern "C" void kernel_launch(void* const* d_in, const int* in_sizes, int n_in,
                              void* d_out, int out_size, void* d_ws, size_t ws_size,
                              hipStream_t stream) {
  const float* x  = (const float*)d_in[0];
  const float* Wq = (const float*)d_in[1];
  const float* Wk = (const float*)d_in[2];
  const float* Wv = (const float*)d_in[3];
  const float* pw = (const float*)d_in[4];
  const float* pb = (const float*)d_in[5];
  float* out = (float*)d_out;

  char* ws = (char*)d_ws;
  u16* Xb   = (u16*)(ws);                       // 16 MB (dead after GEMM1)
  u16* VTg  = (u16*)(ws);                       // 16 MB (overlays Xb)
  u16* Wcat = (u16*)(ws + (16u << 20));         // 6 MB
  u16* PWt  = (u16*)(ws + (22u << 20));         // 2 MB
  u16* QKV  = (u16*)(ws + (24u << 20));         // 48 MB
  u16* ATT  = (u16*)(ws + (72u << 20));         // 16 MB (total 88 MB)

  prep_kernel<<<9984, 256, 0, stream>>>(x, Wq, Wk, Wv, pw, Xb, Wcat, PWt);

  gemm3b<1><<<768, 512, 0, stream>>>(Xb, Wcat, QKV, nullptr, 8192, 3072, 1024, 1024);

  vt_build<<<2048, 256, 0, stream>>>(QKV, VTg);

  attn_kernel<<<512, 512, 0, stream>>>(QKV, VTg, ATT);

  gemm3b<0><<<256, 512, 0, stream>>>(ATT, PWt, out, pb, 8192, 1024, 1024, 0);
}

// Round 11
// 165.862 us; speedup vs baseline: 1.9622x; 1.0045x over previous
//
#include <hip/hip_runtime.h>

typedef unsigned short u16;
typedef __attribute__((ext_vector_type(8))) __bf16 bf16x8;
typedef __attribute__((ext_vector_type(4))) float f32x4;
typedef __attribute__((ext_vector_type(16))) float f32x16;
typedef __attribute__((ext_vector_type(4))) unsigned short ushort4v;
typedef __attribute__((ext_vector_type(2))) unsigned uint2v;

__device__ __forceinline__ u16 f2bf(float f) {
  unsigned u = __builtin_bit_cast(unsigned, f);
  u += 0x7fffu + ((u >> 16) & 1u);
  return (u16)(u >> 16);
}

__device__ __forceinline__ float exp2_hw(float x) {
  float r; asm("v_exp_f32 %0, %1" : "=v"(r) : "v"(x)); return r;
}
__device__ __forceinline__ unsigned cvt_pk_bf16(float a, float b) {
  unsigned r; asm("v_cvt_pk_bf16_f32 %0, %1, %2" : "=v"(r) : "v"(a), "v"(b)); return r;
}

__device__ __forceinline__ void gload_lds16(const void* g, void* l) {
  __builtin_amdgcn_global_load_lds(
      (__attribute__((address_space(1))) void*)g,
      (__attribute__((address_space(3))) void*)l, 16, 0, 0);
}

__device__ __forceinline__ void BAR() {
  asm volatile("" ::: "memory");
  __builtin_amdgcn_s_barrier();
  asm volatile("" ::: "memory");
}

#define MFMA16(a, b, c) __builtin_amdgcn_mfma_f32_16x16x32_bf16(a, b, c, 0, 0, 0)
#define MFMA32(a, b, c) __builtin_amdgcn_mfma_f32_32x32x16_bf16(a, b, c, 0, 0, 0)

// scale folded into Q at GEMM1 epilogue: 1/sqrt(64) * log2(e)
#define QSCALE 0.1803368801111204f

// ---------------- merged prep kernel ----------------

__global__ __launch_bounds__(256)
void prep_kernel(const float* __restrict__ x, const float* __restrict__ Wq,
                 const float* __restrict__ Wk, const float* __restrict__ Wv,
                 const float* __restrict__ pw, u16* __restrict__ Xb,
                 u16* __restrict__ Wcat, u16* __restrict__ PWt) {
  const int b = blockIdx.x, tid = threadIdx.x;
  if (b < 8192) {
    int i = b * 256 + tid;
    float4 v = ((const float4*)x)[i];
    union { u16 u[4]; uint2 v2; } r;
    r.u[0] = f2bf(v.x); r.u[1] = f2bf(v.y); r.u[2] = f2bf(v.z); r.u[3] = f2bf(v.w);
    ((uint2*)Xb)[i] = r.v2;
  } else if (b < 8960) {
    __shared__ u16 lds[64 * 68];
    int bb = b - 8192;
    int sel = bb >> 8, rem = bb & 255;
    int h = rem >> 4, e0 = (rem & 15) * 64;
    const float* W = (sel == 0) ? Wq : (sel == 1) ? Wk : Wv;
    const float* src = W + ((size_t)h * 1024 + e0) * 64;
#pragma unroll
    for (int i = 0; i < 4; i++) {
      int idx = i * 1024 + tid * 4;
      int e = idx >> 6, hs = idx & 63;
      float4 v = *(const float4*)&src[idx];
      u16* d = &lds[e * 68 + hs];
      d[0] = f2bf(v.x); d[1] = f2bf(v.y); d[2] = f2bf(v.z); d[3] = f2bf(v.w);
    }
    __syncthreads();
#pragma unroll
    for (int i = 0; i < 2; i++) {
      int u = i * 256 + tid;
      int hs = u >> 3, ec = u & 7;
      union { u16 q[8]; uint4 v; } ou;
#pragma unroll
      for (int e = 0; e < 8; e++) ou.q[e] = lds[(ec * 8 + e) * 68 + hs];
      size_t n = (size_t)sel * 1024 + h * 64 + hs;
      *(uint4*)&Wcat[n * 1024 + e0 + ec * 8] = ou.v;
    }
  } else {
    int i = (b - 8960) * 256 + tid;
    float4 v = ((const float4*)pw)[i];
    union { u16 u[4]; uint2 v2; } r;
    r.u[0] = f2bf(v.x); r.u[1] = f2bf(v.y); r.u[2] = f2bf(v.z); r.u[3] = f2bf(v.w);
    ((uint2*)PWt)[i] = r.v2;
  }
}

// ---------------- triple-buffered 128x256 GEMM, 2 sub-phases per K-tile ----

template<int OUT_BF16>
__global__ __launch_bounds__(512, 2)
void gemm3b(const u16* __restrict__ A, const u16* __restrict__ BT,
            void* __restrict__ Cout, const float* __restrict__ bias,
            int M, int N, int K, int qcols) {
  __shared__ u16 a_lds[3][128 * 64];
  __shared__ u16 b_lds[3][256 * 64];
  const int xcd = blockIdx.x & 7;
  const int local = blockIdx.x >> 3;
  const int by = xcd * 8 + (local & 7);   // M-chunk of 8 blocks per XCD
  const int bx = local >> 3;              // N-panel, slow
  const int tid = threadIdx.x;
  const int lane = tid & 63;
  const int w = tid >> 6;
  const int wr = w >> 2, wc = w & 3;
  const int mBase = by * 128, nBase = bx * 256;
  const int l15 = lane & 15, l4 = lane >> 4;
  const int nkt = K >> 6;

  f32x4 acc[4][4] = {};

  auto STAGE_A = [&](int s, int kt) {
#pragma unroll
    for (int j = 0; j < 2; j++) {
      int e = j * 4096 + tid * 8;
      int row = e >> 6;
      int c = ((e >> 3) & 7) ^ (row & 7);
      gload_lds16(A + (size_t)(mBase + row) * K + kt * 64 + c * 8, &a_lds[s][e]);
    }
  };
  auto STAGE_B = [&](int s, int kt) {
#pragma unroll
    for (int j = 0; j < 4; j++) {
      int e = j * 4096 + tid * 8;
      int row = e >> 6;
      int c = ((e >> 3) & 7) ^ (row & 7);
      gload_lds16(BT + (size_t)(nBase + row) * K + kt * 64 + c * 8, &b_lds[s][e]);
    }
  };

  STAGE_A(0, 0); STAGE_B(0, 0);
  STAGE_A(1, 1); STAGE_B(1, 1);
  asm volatile("s_waitcnt vmcnt(6)" ::: "memory");
  BAR();

  int s0 = 0, s1 = 1, s2 = 2;
  for (int t = 0; t < nkt; t++) {
    const int t2 = (t + 2 < nkt) ? t + 2 : t + 2 - nkt;
    bf16x8 AF[4][2], BF[2][2];

#pragma unroll
    for (int m = 0; m < 4; m++) {
      int row = wr * 64 + m * 16 + l15;
#pragma unroll
      for (int ks = 0; ks < 2; ks++) {
        int ch = (ks * 4 + l4) ^ (row & 7);
        AF[m][ks] = *(const bf16x8*)&a_lds[s0][row * 64 + ch * 8];
      }
    }
#pragma unroll
    for (int n = 0; n < 2; n++) {
      int row = wc * 64 + n * 16 + l15;
#pragma unroll
      for (int ks = 0; ks < 2; ks++) {
        int ch = (ks * 4 + l4) ^ (row & 7);
        BF[n][ks] = *(const bf16x8*)&b_lds[s0][row * 64 + ch * 8];
      }
    }
    STAGE_A(s2, t2);
    BAR();
    __builtin_amdgcn_s_setprio(1);
#pragma unroll
    for (int m = 0; m < 4; m++)
#pragma unroll
      for (int n = 0; n < 2; n++) {
        acc[m][n] = MFMA16(AF[m][0], BF[n][0], acc[m][n]);
        acc[m][n] = MFMA16(AF[m][1], BF[n][1], acc[m][n]);
      }
    __builtin_amdgcn_s_setprio(0);

#pragma unroll
    for (int n = 0; n < 2; n++) {
      int row = wc * 64 + 32 + n * 16 + l15;
#pragma unroll
      for (int ks = 0; ks < 2; ks++) {
        int ch = (ks * 4 + l4) ^ (row & 7);
        BF[n][ks] = *(const bf16x8*)&b_lds[s0][row * 64 + ch * 8];
      }
    }
    STAGE_B(s2, t2);
    BAR();
    __builtin_amdgcn_s_setprio(1);
#pragma unroll
    for (int m = 0; m < 4; m++)
#pragma unroll
      for (int n = 0; n < 2; n++) {
        acc[m][2 + n] = MFMA16(AF[m][0], BF[n][0], acc[m][2 + n]);
        acc[m][2 + n] = MFMA16(AF[m][1], BF[n][1], acc[m][2 + n]);
      }
    __builtin_amdgcn_s_setprio(0);

    asm volatile("s_waitcnt vmcnt(6)" ::: "memory");
    BAR();
    int tmp = s0; s0 = s1; s1 = s2; s2 = tmp;
  }

#pragma unroll
  for (int mi = 0; mi < 4; mi++) {
    int row = mBase + wr * 64 + mi * 16 + l4 * 4;
#pragma unroll
    for (int ni = 0; ni < 4; ni++) {
      int col = nBase + wc * 64 + ni * 16 + l15;
      float scl = (col < qcols) ? QSCALE : 1.f;
#pragma unroll
      for (int j = 0; j < 4; j++) {
        float v = acc[mi][ni][j];
        if (OUT_BF16) {
          ((u16*)Cout)[(size_t)(row + j) * N + col] = f2bf(v * scl);
        } else {
          ((float*)Cout)[(size_t)(row + j) * N + col] = v + bias[col];
        }
      }
    }
  }
}

// ---------------- V transpose: VT[hb][d][t] from QKV V-section ----------------

__global__ __launch_bounds__(256)
void vt_build(const u16* __restrict__ qkv, u16* __restrict__ vt) {
  __shared__ u16 lds[64 * 66];
  const int hb = blockIdx.x >> 5, tc = blockIdx.x & 31;
  const int t0 = tc * 64, tid = threadIdx.x;
#pragma unroll
  for (int i = 0; i < 2; i++) {
    int idx = i * 2048 + tid * 8;
    int tl = idx >> 6, d0 = idx & 63;
    int r = hb * 2048 + t0 + tl;
    const u16* src = &qkv[(size_t)(r >> 4) * 3072 + 2048 + (r & 15) * 64 + d0];
    uint4 v = *(const uint4*)src;
    u16* dst = &lds[tl * 66 + d0];
    *(unsigned*)(dst + 0) = v.x; *(unsigned*)(dst + 2) = v.y;
    *(unsigned*)(dst + 4) = v.z; *(unsigned*)(dst + 6) = v.w;
  }
  __syncthreads();
#pragma unroll
  for (int i = 0; i < 2; i++) {
    int idx = i * 2048 + tid * 8;
    int d = idx >> 6, tl0 = idx & 63;
    union { u16 u[8]; uint4 v; } ou;
#pragma unroll
    for (int e = 0; e < 8; e++) ou.u[e] = lds[(tl0 + e) * 66 + d];
    *(uint4*)&vt[(size_t)hb * 131072 + (size_t)d * 2048 + t0 + tl0] = ou.v;
  }
}

// ---------------- flash attention (causal), 32x32 MFMA, in-register P ------
// Triple-buffered K/V staging with counted vmcnt(2): at tile t, stage t+2
// into the never-read third buffer; t+1's 2 loads proven landed at the
// barrier; no drain-to-0 in the loop (T3/T4).

__global__ __launch_bounds__(512, 3)
void attn_kernel(const u16* __restrict__ qkv, const u16* __restrict__ vtg,
                 u16* __restrict__ att) {
  __shared__ u16 k_lds[3][64 * 64];
  __shared__ u16 v_lds[3][64 * 64];

  const int xcd = blockIdx.x & 7;
  const int c = blockIdx.x >> 3;
  const int hb = xcd * 8 + (c & 7);
  const int qb = 7 - (c >> 3);
  const int tid = threadIdx.x;
  const int lane = tid & 63, w = tid >> 6;
  const int l31 = lane & 31, l5 = lane >> 5;
  const int qbase = qb * 256 + w * 32;
  const int nkt = 4 * qb + 4;

  bf16x8 qf[4];
  {
    int t = qbase + l31;
    int r = hb * 2048 + t;
    size_t base = (size_t)(r >> 4) * 3072 + (r & 15) * 64;
#pragma unroll
    for (int d = 0; d < 4; d++)
      qf[d] = *(const bf16x8*)&qkv[base + d * 16 + l5 * 8];
  }

  f32x16 o0 = {}, o1 = {};
  float lp = 0.f;

  auto STAGE = [&](int buf, int kt) {
    {
      int U = tid * 8;
      int row = U >> 6;
      int chunk = ((U >> 3) & 7) ^ (row & 7);
      int rK = hb * 2048 + kt * 64 + row;
      gload_lds16(&qkv[(size_t)(rK >> 4) * 3072 + 1024 + (rK & 15) * 64 + chunk * 8],
                  &k_lds[buf][U]);
    }
    {
      int U = tid * 8;
      int row = U >> 6;
      int chunk = ((U >> 3) & 7) ^ (row & 7);
      gload_lds16(&vtg[(size_t)hb * 131072 + (size_t)row * 2048 + kt * 64 + chunk * 8],
                  &v_lds[buf][U]);
    }
  };

  // prologue: stage tile0 -> buf0, tile1 -> buf1; wait tile0 only (2 in flight)
  STAGE(0, 0);
  if (nkt > 1) STAGE(1, 1);
  asm volatile("s_waitcnt vmcnt(2)" ::: "memory");
  BAR();

  int s0 = 0, s1 = 1, s2 = 2;
  for (int kt = 0; kt < nkt; kt++) {
    const bool pre = (kt + 2 < nkt);
    if (pre) STAGE(s2, kt + 2);
    const int cur = s0;
    const bool active = (kt * 64 <= qbase + 31);
    if (active) {
      const bool full = (kt * 64 + 63 <= qbase);
      const int q = qbase + l31;
#pragma unroll
      for (int kb = 0; kb < 2; kb++) {
        int krow = kb * 32 + l31;
        int ksw = krow & 7;
        f32x16 st = {};
        __builtin_amdgcn_s_setprio(1);
#pragma unroll
        for (int t = 0; t < 4; t++) {
          bf16x8 kf = *(const bf16x8*)&k_lds[cur][krow * 64 + ((t * 2 + l5) ^ ksw) * 8];
          st = MFMA32(kf, qf[t], st);
        }
        __builtin_amdgcn_s_setprio(0);
        float p[16];
#pragma unroll
        for (int r = 0; r < 16; r++) {
          float v = st[r];
          if (!full) {
            int k = kt * 64 + kb * 32 + (r & 3) + 8 * (r >> 2) + 4 * l5;
            v = (k > q) ? -INFINITY : v;
          }
          p[r] = exp2_hw(v);
          lp += p[r];
        }
#pragma unroll
        for (int kc = 0; kc < 2; kc++) {
          unsigned w0 = cvt_pk_bf16(p[kc * 8 + 0], p[kc * 8 + 1]);
          unsigned w1 = cvt_pk_bf16(p[kc * 8 + 2], p[kc * 8 + 3]);
          unsigned w2 = cvt_pk_bf16(p[kc * 8 + 4], p[kc * 8 + 5]);
          unsigned w3 = cvt_pk_bf16(p[kc * 8 + 6], p[kc * 8 + 7]);
          uint2v sw0 = __builtin_amdgcn_permlane32_swap(w0, w2, false, false);
          uint2v sw1 = __builtin_amdgcn_permlane32_swap(w1, w3, false, false);
          union { unsigned u[4]; bf16x8 v; } pf;
          pf.u[0] = sw0.x; pf.u[1] = sw1.x; pf.u[2] = sw0.y; pf.u[3] = sw1.y;
          __builtin_amdgcn_s_setprio(1);
          {
            int row0 = l31;
            int ch0 = (kb * 4 + kc * 2 + l5) ^ (row0 & 7);
            bf16x8 vf0 = *(const bf16x8*)&v_lds[cur][row0 * 64 + ch0 * 8];
            o0 = MFMA32(vf0, pf.v, o0);
            int row1 = 32 + l31;
            int ch1 = (kb * 4 + kc * 2 + l5) ^ (row1 & 7);
            bf16x8 vf1 = *(const bf16x8*)&v_lds[cur][row1 * 64 + ch1 * 8];
            o1 = MFMA32(vf1, pf.v, o1);
          }
          __builtin_amdgcn_s_setprio(0);
        }
      }
    }
    // counted wait: t+1's 2 loads landed; t+2's (if issued) stay in flight.
    if (pre) {
      asm volatile("s_waitcnt vmcnt(2)" ::: "memory");
    } else {
      asm volatile("s_waitcnt vmcnt(0)" ::: "memory");
    }
    BAR();
    int tmp = s0; s0 = s1; s1 = s2; s2 = tmp;
  }

  lp += __shfl_xor(lp, 32);
  float rl = 1.f / lp;
  {
    int q = qbase + l31;
    size_t rbase = ((size_t)hb * 2048 + q) * 64;
#pragma unroll
    for (int g = 0; g < 4; g++) {
      uint2 wv;
      wv.x = cvt_pk_bf16(o0[4 * g + 0] * rl, o0[4 * g + 1] * rl);
      wv.y = cvt_pk_bf16(o0[4 * g + 2] * rl, o0[4 * g + 3] * rl);
      *(uint2*)&att[rbase + g * 8 + 4 * l5] = wv;
      uint2 wu;
      wu.x = cvt_pk_bf16(o1[4 * g + 0] * rl, o1[4 * g + 1] * rl);
      wu.y = cvt_pk_bf16(o1[4 * g + 2] * rl, o1[4 * g + 3] * rl);
      *(uint2*)&att[rbase + 32 + g * 8 + 4 * l5] = wu;
    }
  }
}

// ---------------- launch ----------------

extern "C" void kernel_launch(void* const* d_in, const int* in_sizes, int n_in,
                              void* d_out, int out_size, void* d_ws, size_t ws_size,
                              hipStream_t stream) {
  const float* x  = (const float*)d_in[0];
  const float* Wq = (const float*)d_in[1];
  const float* Wk = (const float*)d_in[2];
  const float* Wv = (const float*)d_in[3];
  const float* pw = (const float*)d_in[4];
  const float* pb = (const float*)d_in[5];
  float* out = (float*)d_out;

  char* ws = (char*)d_ws;
  u16* Xb   = (u16*)(ws);                       // 16 MB (dead after GEMM1)
  u16* VTg  = (u16*)(ws);                       // 16 MB (overlays Xb)
  u16* Wcat = (u16*)(ws + (16u << 20));         // 6 MB
  u16* PWt  = (u16*)(ws + (22u << 20));         // 2 MB
  u16* QKV  = (u16*)(ws + (24u << 20));         // 48 MB
  u16* ATT  = (u16*)(ws + (72u << 20));         // 16 MB (total 88 MB)

  prep_kernel<<<9984, 256, 0, stream>>>(x, Wq, Wk, Wv, pw, Xb, Wcat, PWt);

  gemm3b<1><<<768, 512, 0, stream>>>(Xb, Wcat, QKV, nullptr, 8192, 3072, 1024, 1024);

  vt_build<<<2048, 256, 0, stream>>>(QKV, VTg);

  attn_kernel<<<512, 512, 0, stream>>>(QKV, VTg, ATT);

  gemm3b<0><<<256, 512, 0, stream>>>(ATT, PWt, out, pb, 8192, 1024, 1024, 0);
}

// Round 12
// 161.524 us; speedup vs baseline: 2.0149x; 1.0269x over previous
//
#include <hip/hip_runtime.h>

typedef unsigned short u16;
typedef __attribute__((ext_vector_type(8))) __bf16 bf16x8;
typedef __attribute__((ext_vector_type(4))) float f32x4;
typedef __attribute__((ext_vector_type(16))) float f32x16;
typedef __attribute__((ext_vector_type(4))) unsigned short ushort4v;
typedef __attribute__((ext_vector_type(2))) unsigned uint2v;

__device__ __forceinline__ u16 f2bf(float f) {
  unsigned u = __builtin_bit_cast(unsigned, f);
  u += 0x7fffu + ((u >> 16) & 1u);
  return (u16)(u >> 16);
}

__device__ __forceinline__ float exp2_hw(float x) {
  float r; asm("v_exp_f32 %0, %1" : "=v"(r) : "v"(x)); return r;
}
__device__ __forceinline__ unsigned cvt_pk_bf16(float a, float b) {
  unsigned r; asm("v_cvt_pk_bf16_f32 %0, %1, %2" : "=v"(r) : "v"(a), "v"(b)); return r;
}

__device__ __forceinline__ void gload_lds16(const void* g, void* l) {
  __builtin_amdgcn_global_load_lds(
      (__attribute__((address_space(1))) void*)g,
      (__attribute__((address_space(3))) void*)l, 16, 0, 0);
}

__device__ __forceinline__ void BAR() {
  asm volatile("" ::: "memory");
  __builtin_amdgcn_s_barrier();
  asm volatile("" ::: "memory");
}

#define MFMA16(a, b, c) __builtin_amdgcn_mfma_f32_16x16x32_bf16(a, b, c, 0, 0, 0)
#define MFMA32(a, b, c) __builtin_amdgcn_mfma_f32_32x32x16_bf16(a, b, c, 0, 0, 0)

// scale folded into Q at GEMM1 epilogue: 1/sqrt(64) * log2(e)
#define QSCALE 0.1803368801111204f

// ---------------- merged prep kernel ----------------

__global__ __launch_bounds__(256)
void prep_kernel(const float* __restrict__ x, const float* __restrict__ Wq,
                 const float* __restrict__ Wk, const float* __restrict__ Wv,
                 const float* __restrict__ pw, u16* __restrict__ Xb,
                 u16* __restrict__ Wcat, u16* __restrict__ PWt) {
  const int b = blockIdx.x, tid = threadIdx.x;
  if (b < 8192) {
    int i = b * 256 + tid;
    float4 v = ((const float4*)x)[i];
    union { u16 u[4]; uint2 v2; } r;
    r.u[0] = f2bf(v.x); r.u[1] = f2bf(v.y); r.u[2] = f2bf(v.z); r.u[3] = f2bf(v.w);
    ((uint2*)Xb)[i] = r.v2;
  } else if (b < 8960) {
    __shared__ u16 lds[64 * 68];
    int bb = b - 8192;
    int sel = bb >> 8, rem = bb & 255;
    int h = rem >> 4, e0 = (rem & 15) * 64;
    const float* W = (sel == 0) ? Wq : (sel == 1) ? Wk : Wv;
    const float* src = W + ((size_t)h * 1024 + e0) * 64;
#pragma unroll
    for (int i = 0; i < 4; i++) {
      int idx = i * 1024 + tid * 4;
      int e = idx >> 6, hs = idx & 63;
      float4 v = *(const float4*)&src[idx];
      u16* d = &lds[e * 68 + hs];
      d[0] = f2bf(v.x); d[1] = f2bf(v.y); d[2] = f2bf(v.z); d[3] = f2bf(v.w);
    }
    __syncthreads();
#pragma unroll
    for (int i = 0; i < 2; i++) {
      int u = i * 256 + tid;
      int hs = u >> 3, ec = u & 7;
      union { u16 q[8]; uint4 v; } ou;
#pragma unroll
      for (int e = 0; e < 8; e++) ou.q[e] = lds[(ec * 8 + e) * 68 + hs];
      size_t n = (size_t)sel * 1024 + h * 64 + hs;
      *(uint4*)&Wcat[n * 1024 + e0 + ec * 8] = ou.v;
    }
  } else {
    int i = (b - 8960) * 256 + tid;
    float4 v = ((const float4*)pw)[i];
    union { u16 u[4]; uint2 v2; } r;
    r.u[0] = f2bf(v.x); r.u[1] = f2bf(v.y); r.u[2] = f2bf(v.z); r.u[3] = f2bf(v.w);
    ((uint2*)PWt)[i] = r.v2;
  }
}

// ---------------- triple-buffered 128x256 GEMM, 2 sub-phases per K-tile ----

template<int OUT_BF16>
__global__ __launch_bounds__(512, 2)
void gemm3b(const u16* __restrict__ A, const u16* __restrict__ BT,
            void* __restrict__ Cout, const float* __restrict__ bias,
            int M, int N, int K, int qcols) {
  __shared__ u16 a_lds[3][128 * 64];
  __shared__ u16 b_lds[3][256 * 64];
  const int xcd = blockIdx.x & 7;
  const int local = blockIdx.x >> 3;
  const int by = xcd * 8 + (local & 7);   // M-chunk of 8 blocks per XCD
  const int bx = local >> 3;              // N-panel, slow
  const int tid = threadIdx.x;
  const int lane = tid & 63;
  const int w = tid >> 6;
  const int wr = w >> 2, wc = w & 3;
  const int mBase = by * 128, nBase = bx * 256;
  const int l15 = lane & 15, l4 = lane >> 4;
  const int nkt = K >> 6;

  f32x4 acc[4][4] = {};

  auto STAGE_A = [&](int s, int kt) {
#pragma unroll
    for (int j = 0; j < 2; j++) {
      int e = j * 4096 + tid * 8;
      int row = e >> 6;
      int c = ((e >> 3) & 7) ^ (row & 7);
      gload_lds16(A + (size_t)(mBase + row) * K + kt * 64 + c * 8, &a_lds[s][e]);
    }
  };
  auto STAGE_B = [&](int s, int kt) {
#pragma unroll
    for (int j = 0; j < 4; j++) {
      int e = j * 4096 + tid * 8;
      int row = e >> 6;
      int c = ((e >> 3) & 7) ^ (row & 7);
      gload_lds16(BT + (size_t)(nBase + row) * K + kt * 64 + c * 8, &b_lds[s][e]);
    }
  };

  STAGE_A(0, 0); STAGE_B(0, 0);
  STAGE_A(1, 1); STAGE_B(1, 1);
  asm volatile("s_waitcnt vmcnt(6)" ::: "memory");
  BAR();

  int s0 = 0, s1 = 1, s2 = 2;
  for (int t = 0; t < nkt; t++) {
    const int t2 = (t + 2 < nkt) ? t + 2 : t + 2 - nkt;
    bf16x8 AF[4][2], BF[2][2];

#pragma unroll
    for (int m = 0; m < 4; m++) {
      int row = wr * 64 + m * 16 + l15;
#pragma unroll
      for (int ks = 0; ks < 2; ks++) {
        int ch = (ks * 4 + l4) ^ (row & 7);
        AF[m][ks] = *(const bf16x8*)&a_lds[s0][row * 64 + ch * 8];
      }
    }
#pragma unroll
    for (int n = 0; n < 2; n++) {
      int row = wc * 64 + n * 16 + l15;
#pragma unroll
      for (int ks = 0; ks < 2; ks++) {
        int ch = (ks * 4 + l4) ^ (row & 7);
        BF[n][ks] = *(const bf16x8*)&b_lds[s0][row * 64 + ch * 8];
      }
    }
    STAGE_A(s2, t2);
    BAR();
    __builtin_amdgcn_s_setprio(1);
#pragma unroll
    for (int m = 0; m < 4; m++)
#pragma unroll
      for (int n = 0; n < 2; n++) {
        acc[m][n] = MFMA16(AF[m][0], BF[n][0], acc[m][n]);
        acc[m][n] = MFMA16(AF[m][1], BF[n][1], acc[m][n]);
      }
    __builtin_amdgcn_s_setprio(0);

#pragma unroll
    for (int n = 0; n < 2; n++) {
      int row = wc * 64 + 32 + n * 16 + l15;
#pragma unroll
      for (int ks = 0; ks < 2; ks++) {
        int ch = (ks * 4 + l4) ^ (row & 7);
        BF[n][ks] = *(const bf16x8*)&b_lds[s0][row * 64 + ch * 8];
      }
    }
    STAGE_B(s2, t2);
    BAR();
    __builtin_amdgcn_s_setprio(1);
#pragma unroll
    for (int m = 0; m < 4; m++)
#pragma unroll
      for (int n = 0; n < 2; n++) {
        acc[m][2 + n] = MFMA16(AF[m][0], BF[n][0], acc[m][2 + n]);
        acc[m][2 + n] = MFMA16(AF[m][1], BF[n][1], acc[m][2 + n]);
      }
    __builtin_amdgcn_s_setprio(0);

    asm volatile("s_waitcnt vmcnt(6)" ::: "memory");
    BAR();
    int tmp = s0; s0 = s1; s1 = s2; s2 = tmp;
  }

#pragma unroll
  for (int mi = 0; mi < 4; mi++) {
    int row = mBase + wr * 64 + mi * 16 + l4 * 4;
#pragma unroll
    for (int ni = 0; ni < 4; ni++) {
      int col = nBase + wc * 64 + ni * 16 + l15;
      float scl = (col < qcols) ? QSCALE : 1.f;
#pragma unroll
      for (int j = 0; j < 4; j++) {
        float v = acc[mi][ni][j];
        if (OUT_BF16) {
          ((u16*)Cout)[(size_t)(row + j) * N + col] = f2bf(v * scl);
        } else {
          ((float*)Cout)[(size_t)(row + j) * N + col] = v + bias[col];
        }
      }
    }
  }
}

// ---------------- V transpose: VT[hb][d][t] from QKV V-section ----------------

__global__ __launch_bounds__(256)
void vt_build(const u16* __restrict__ qkv, u16* __restrict__ vt) {
  __shared__ u16 lds[64 * 66];
  const int hb = blockIdx.x >> 5, tc = blockIdx.x & 31;
  const int t0 = tc * 64, tid = threadIdx.x;
#pragma unroll
  for (int i = 0; i < 2; i++) {
    int idx = i * 2048 + tid * 8;
    int tl = idx >> 6, d0 = idx & 63;
    int r = hb * 2048 + t0 + tl;
    const u16* src = &qkv[(size_t)(r >> 4) * 3072 + 2048 + (r & 15) * 64 + d0];
    uint4 v = *(const uint4*)src;
    u16* dst = &lds[tl * 66 + d0];
    *(unsigned*)(dst + 0) = v.x; *(unsigned*)(dst + 2) = v.y;
    *(unsigned*)(dst + 4) = v.z; *(unsigned*)(dst + 6) = v.w;
  }
  __syncthreads();
#pragma unroll
  for (int i = 0; i < 2; i++) {
    int idx = i * 2048 + tid * 8;
    int d = idx >> 6, tl0 = idx & 63;
    union { u16 u[8]; uint4 v; } ou;
#pragma unroll
    for (int e = 0; e < 8; e++) ou.u[e] = lds[(tl0 + e) * 66 + d];
    *(uint4*)&vt[(size_t)hb * 131072 + (size_t)d * 2048 + t0 + tl0] = ou.v;
  }
}

// ---------------- flash attention (causal), 32x32 MFMA, in-register P ------
// 4-wave blocks (128 q-rows), qb 0..15, grid 1024: small scheduling quanta so
// short blocks retire and backfill (LPT works). Double-buffered K/V (32 KB)
// -> up to 5 blocks/CU = 20 waves/CU.

__global__ __launch_bounds__(256)
void attn_kernel(const u16* __restrict__ qkv, const u16* __restrict__ vtg,
                 u16* __restrict__ att) {
  __shared__ u16 k_lds[2][64 * 64];
  __shared__ u16 v_lds[2][64 * 64];

  const int xcd = blockIdx.x & 7;
  const int c = blockIdx.x >> 3;          // 0..127 within XCD
  const int hb = xcd * 8 + (c & 7);       // hb-contiguous per XCD
  const int qb = 15 - (c >> 3);           // heavy blocks first (LPT)
  const int tid = threadIdx.x;
  const int lane = tid & 63, w = tid >> 6;
  const int l31 = lane & 31, l5 = lane >> 5;
  const int qbase = qb * 128 + w * 32;
  const int nkt = 2 * qb + 2;

  bf16x8 qf[4];
  {
    int t = qbase + l31;
    int r = hb * 2048 + t;
    size_t base = (size_t)(r >> 4) * 3072 + (r & 15) * 64;
#pragma unroll
    for (int d = 0; d < 4; d++)
      qf[d] = *(const bf16x8*)&qkv[base + d * 16 + l5 * 8];
  }

  f32x16 o0 = {}, o1 = {};
  float lp = 0.f;

  auto STAGE = [&](int buf, int kt) {
#pragma unroll
    for (int i = 0; i < 2; i++) {
      int U = i * 2048 + tid * 8;
      int row = U >> 6;
      int chunk = ((U >> 3) & 7) ^ (row & 7);
      int rK = hb * 2048 + kt * 64 + row;
      gload_lds16(&qkv[(size_t)(rK >> 4) * 3072 + 1024 + (rK & 15) * 64 + chunk * 8],
                  &k_lds[buf][U]);
    }
#pragma unroll
    for (int i = 0; i < 2; i++) {
      int U = i * 2048 + tid * 8;
      int row = U >> 6;
      int chunk = ((U >> 3) & 7) ^ (row & 7);
      gload_lds16(&vtg[(size_t)hb * 131072 + (size_t)row * 2048 + kt * 64 + chunk * 8],
                  &v_lds[buf][U]);
    }
  };

  STAGE(0, 0);
  asm volatile("s_waitcnt vmcnt(0)" ::: "memory");
  BAR();

  for (int kt = 0; kt < nkt; kt++) {
    if (kt + 1 < nkt) STAGE((kt + 1) & 1, kt + 1);
    const int cur = kt & 1;
    const bool active = (kt * 64 <= qbase + 31);
    if (active) {
      const bool full = (kt * 64 + 63 <= qbase);
      const int q = qbase + l31;
#pragma unroll
      for (int kb = 0; kb < 2; kb++) {
        int krow = kb * 32 + l31;
        int ksw = krow & 7;
        f32x16 st = {};
        __builtin_amdgcn_s_setprio(1);
#pragma unroll
        for (int t = 0; t < 4; t++) {
          bf16x8 kf = *(const bf16x8*)&k_lds[cur][krow * 64 + ((t * 2 + l5) ^ ksw) * 8];
          st = MFMA32(kf, qf[t], st);
        }
        __builtin_amdgcn_s_setprio(0);
        float p[16];
#pragma unroll
        for (int r = 0; r < 16; r++) {
          float v = st[r];
          if (!full) {
            int k = kt * 64 + kb * 32 + (r & 3) + 8 * (r >> 2) + 4 * l5;
            v = (k > q) ? -INFINITY : v;
          }
          p[r] = exp2_hw(v);
          lp += p[r];
        }
#pragma unroll
        for (int kc = 0; kc < 2; kc++) {
          unsigned w0 = cvt_pk_bf16(p[kc * 8 + 0], p[kc * 8 + 1]);
          unsigned w1 = cvt_pk_bf16(p[kc * 8 + 2], p[kc * 8 + 3]);
          unsigned w2 = cvt_pk_bf16(p[kc * 8 + 4], p[kc * 8 + 5]);
          unsigned w3 = cvt_pk_bf16(p[kc * 8 + 6], p[kc * 8 + 7]);
          uint2v sw0 = __builtin_amdgcn_permlane32_swap(w0, w2, false, false);
          uint2v sw1 = __builtin_amdgcn_permlane32_swap(w1, w3, false, false);
          union { unsigned u[4]; bf16x8 v; } pf;
          pf.u[0] = sw0.x; pf.u[1] = sw1.x; pf.u[2] = sw0.y; pf.u[3] = sw1.y;
          __builtin_amdgcn_s_setprio(1);
          {
            int row0 = l31;
            int ch0 = (kb * 4 + kc * 2 + l5) ^ (row0 & 7);
            bf16x8 vf0 = *(const bf16x8*)&v_lds[cur][row0 * 64 + ch0 * 8];
            o0 = MFMA32(vf0, pf.v, o0);
            int row1 = 32 + l31;
            int ch1 = (kb * 4 + kc * 2 + l5) ^ (row1 & 7);
            bf16x8 vf1 = *(const bf16x8*)&v_lds[cur][row1 * 64 + ch1 * 8];
            o1 = MFMA32(vf1, pf.v, o1);
          }
          __builtin_amdgcn_s_setprio(0);
        }
      }
    }
    asm volatile("s_waitcnt vmcnt(0)" ::: "memory");
    BAR();
  }

  lp += __shfl_xor(lp, 32);
  float rl = 1.f / lp;
  {
    int q = qbase + l31;
    size_t rbase = ((size_t)hb * 2048 + q) * 64;
#pragma unroll
    for (int g = 0; g < 4; g++) {
      uint2 wv;
      wv.x = cvt_pk_bf16(o0[4 * g + 0] * rl, o0[4 * g + 1] * rl);
      wv.y = cvt_pk_bf16(o0[4 * g + 2] * rl, o0[4 * g + 3] * rl);
      *(uint2*)&att[rbase + g * 8 + 4 * l5] = wv;
      uint2 wu;
      wu.x = cvt_pk_bf16(o1[4 * g + 0] * rl, o1[4 * g + 1] * rl);
      wu.y = cvt_pk_bf16(o1[4 * g + 2] * rl, o1[4 * g + 3] * rl);
      *(uint2*)&att[rbase + 32 + g * 8 + 4 * l5] = wu;
    }
  }
}

// ---------------- launch ----------------

extern "C" void kernel_launch(void* const* d_in, const int* in_sizes, int n_in,
                              void* d_out, int out_size, void* d_ws, size_t ws_size,
                              hipStream_t stream) {
  const float* x  = (const float*)d_in[0];
  const float* Wq = (const float*)d_in[1];
  const float* Wk = (const float*)d_in[2];
  const float* Wv = (const float*)d_in[3];
  const float* pw = (const float*)d_in[4];
  const float* pb = (const float*)d_in[5];
  float* out = (float*)d_out;

  char* ws = (char*)d_ws;
  u16* Xb   = (u16*)(ws);                       // 16 MB (dead after GEMM1)
  u16* VTg  = (u16*)(ws);                       // 16 MB (overlays Xb)
  u16* Wcat = (u16*)(ws + (16u << 20));         // 6 MB
  u16* PWt  = (u16*)(ws + (22u << 20));         // 2 MB
  u16* QKV  = (u16*)(ws + (24u << 20));         // 48 MB
  u16* ATT  = (u16*)(ws + (72u << 20));         // 16 MB (total 88 MB)

  prep_kernel<<<9984, 256, 0, stream>>>(x, Wq, Wk, Wv, pw, Xb, Wcat, PWt);

  gemm3b<1><<<768, 512, 0, stream>>>(Xb, Wcat, QKV, nullptr, 8192, 3072, 1024, 1024);

  vt_build<<<2048, 256, 0, stream>>>(QKV, VTg);

  attn_kernel<<<1024, 256, 0, stream>>>(QKV, VTg, ATT);

  gemm3b<0><<<256, 512, 0, stream>>>(ATT, PWt, out, pb, 8192, 1024, 1024, 0);
}